// Round 7
// baseline (449.056 us; speedup 1.0000x reference)
//
#include <hip/hip_runtime.h>

#define N_NODES 100000
#define N_EDGES 1000000
#define N_GRAPHS 512
#define N_CLS 10
#define BN_EPS 1e-5f

#define LB_NB 200     // lookback-scan blocks (200*512 >= 100000); all co-resident
#define NTILES 1563   // ceil(100000/64)
#define SCHUNK 320    // per-wave staged src ids (strip slice ~Poisson(160))

typedef _Float16 half8 __attribute__((ext_vector_type(8)));
typedef _Float16 half4v __attribute__((ext_vector_type(4)));
typedef float floatx4 __attribute__((ext_vector_type(4)));

// ---------------------------------------------------------------- prep
// Fused: x->fp16 | deg-hist+rank | graph bounds | W pack (f16 hi/lo B-frags) | biases.
// deg/status/doneCnt/pooled zeroed by hipMemsetAsync before this kernel.
__global__ __launch_bounds__(256) void prep_kernel(
    const float* __restrict__ x, _Float16* __restrict__ xh,
    const int* __restrict__ batch, const int* __restrict__ dstI,
    int* __restrict__ deg, int* __restrict__ rank,
    const float* __restrict__ w0a, const float* __restrict__ b0a,
    const float* __restrict__ g0, const float* __restrict__ be0,
    const float* __restrict__ m0, const float* __restrict__ v0,
    const float* __restrict__ w0b,
    const float* __restrict__ w1a, const float* __restrict__ b1a,
    const float* __restrict__ g1, const float* __restrict__ be1,
    const float* __restrict__ m1, const float* __restrict__ v1,
    const float* __restrict__ w1b,
    int* __restrict__ gstart,
    _Float16* __restrict__ wHi, _Float16* __restrict__ wLo,
    float* __restrict__ b1p0, float* __restrict__ b1p1) {
    const int gid = blockIdx.x * 256 + threadIdx.x;

    if (gid < 1600000) {  // x -> fp16 (6.4M elems as float4 -> half4)
        float4 v = ((const float4*)x)[gid];
        half4v h = {(_Float16)v.x, (_Float16)v.y, (_Float16)v.z, (_Float16)v.w};
        ((half4v*)xh)[gid] = h;
    }

    if (gid < N_EDGES)  // histogram + per-edge rank within dst bucket
        rank[gid] = atomicAdd(&deg[dstI[gid]], 1);

    if (gid <= N_NODES) {  // graph boundaries from sorted batch
        int bcur = (gid < N_NODES) ? batch[gid] : N_GRAPHS;
        int bprev = (gid > 0) ? batch[gid - 1] : -1;
        for (int g = bprev + 1; g <= bcur; ++g) gstart[g] = gid;
    }

    if (gid < 16384) {  // W frag pack: [mat(4)][k0(2)][c(4)][lane(64)][jj(8)]
        const int e = gid & 4095, mat = gid >> 12;
        const int jj = e & 7, lane = (e >> 3) & 63, c = (e >> 9) & 3, k0 = (e >> 11) & 1;
        const int k = k0 * 32 + (lane >> 4) * 8 + jj;
        const int col = c * 16 + (lane & 15);
        float val;
        if (mat == 0)      val = w0a[k * 64 + col] * (rsqrtf(v0[col] + BN_EPS) * g0[col]);
        else if (mat == 1) val = w0b[k * 64 + col];
        else if (mat == 2) val = w1a[k * 64 + col] * (rsqrtf(v1[col] + BN_EPS) * g1[col]);
        else               val = w1b[k * 64 + col];
        _Float16 hi = (_Float16)val;
        wHi[gid] = hi;
        wLo[gid] = (_Float16)(val - (float)hi);
    }

    if (gid >= 16384 && gid < 16512) {  // BN-folded biases
        int t = gid - 16384;
        if (t < 64) {
            float s = rsqrtf(v0[t] + BN_EPS) * g0[t];
            b1p0[t] = (b0a[t] - m0[t]) * s + be0[t];
        } else {
            t -= 64;
            float s = rsqrtf(v1[t] + BN_EPS) * g1[t];
            b1p1[t] = (b1a[t] - m1[t]) * s + be1[t];
        }
    }
}

// ---------------------------------------------------------------- single-pass scan
// Decoupled lookback: 200 blocks (all co-resident on 256 CUs -> spin is safe).
// status[b] packs (flag<<32)|value; flag 1 = aggregate, 2 = inclusive prefix.
__global__ __launch_bounds__(256) void scan_lb_kernel(const int* __restrict__ deg,
                                                      unsigned long long* __restrict__ status,
                                                      int* __restrict__ rowptr) {
    __shared__ int sh[256];
    __shared__ int sbase;
    const int blk = blockIdx.x;
    const int t = threadIdx.x;
    const int i0 = blk * 512 + 2 * t, i1 = i0 + 1;
    const int d0 = (i0 < N_NODES) ? deg[i0] : 0;
    const int d1 = (i1 < N_NODES) ? deg[i1] : 0;
    const int p = d0 + d1;
    sh[t] = p;
    __syncthreads();
#pragma unroll
    for (int off = 1; off < 256; off <<= 1) {
        int u = (t >= off) ? sh[t - off] : 0;
        __syncthreads();
        sh[t] += u;
        __syncthreads();
    }
    const int agg = sh[255];
    if (t == 0) {
        if (blk == 0) {
            atomicExch(&status[0], (2ULL << 32) | (unsigned)agg);
            sbase = 0;
        } else {
            atomicExch(&status[blk], (1ULL << 32) | (unsigned)agg);
            int base = 0;
            int jb = blk - 1;
            while (jb >= 0) {
                unsigned long long s;
                do { s = atomicAdd(&status[jb], 0ULL); } while ((s >> 32) == 0);
                base += (int)(unsigned)s;
                if ((s >> 32) == 2ULL) break;
                --jb;
            }
            atomicExch(&status[blk], (2ULL << 32) | (unsigned)(base + agg));
            sbase = base;
        }
    }
    __syncthreads();
    const int excl = sbase + sh[t] - p;
    if (i0 < N_NODES) rowptr[i0] = excl;
    if (i1 < N_NODES) rowptr[i1] = excl + d0;
    if (blk == LB_NB - 1 && t == 255) rowptr[N_NODES] = N_EDGES;
}

__global__ __launch_bounds__(256) void fill_kernel(const int* __restrict__ srcI,
                                                   const int* __restrict__ dstI,
                                                   const int* __restrict__ rank,
                                                   const int* __restrict__ rowptr,
                                                   int* __restrict__ sortedSrc) {
    int e = blockIdx.x * 256 + threadIdx.x;
    if (e >= N_EDGES) return;
    sortedSrc[rowptr[dstI[e]] + rank[e]] = srcI[e];
}

// ---------------------------------------------------------------- fused conv (MFMA, fp16)
// Block = 4 waves x 16-node strips. Gather: lane = (edge-subindex j>>4, feature-chunk j&15),
// each lane loads half4 (8B) -> 4 edges (full 128B rows) per wave instruction. Edge ids are
// read per-lane from the LDS-staged CSR slice (no readlane ladder). Two rows' loads are
// issued per batch before any wait. Validity recomputed at consume (no mask storage).
// MLP: split-f16 3-MFMA per linear (unchanged). conv1 pools and the LAST block runs the
// classifier in-kernel (device-scope counter + atomic reads of pooled).
template <int POOL>
__global__ __launch_bounds__(256) void conv_mfma(
    const _Float16* __restrict__ in, const int* __restrict__ rowptr,
    const int* __restrict__ srcList,
    const _Float16* __restrict__ wH1, const _Float16* __restrict__ wL1,
    const _Float16* __restrict__ wH2, const _Float16* __restrict__ wL2,
    const float* __restrict__ b1, const float* __restrict__ b2,
    _Float16* __restrict__ out, const int* __restrict__ batch,
    float* __restrict__ pooled,
    const float* __restrict__ wc, const float* __restrict__ bc,
    const int* __restrict__ gstart, int* __restrict__ doneCnt,
    float* __restrict__ outF) {
    __shared__ __align__(16) _Float16 scratch[4][2304];  // per-wave aggH|aggL -> hH|hL -> oT
    __shared__ int ldsSrc[4][SCHUNK];
    __shared__ float pooledLoc[8 * 64];
    __shared__ int bIds[64];
    __shared__ int maxSlot;
    __shared__ int amLast;

    const int tid = threadIdx.x;
    const int j = tid & 63, wv = tid >> 6;
    const int eoff = j >> 4;    // edge sub-index within a 4-edge load group
    const int lf = j & 15;      // feature chunk (4 features)
    const int base = blockIdx.x * 64;
    const int strip0 = base + wv * 16;

    if (POOL) {
        pooledLoc[tid] = 0.f;
        pooledLoc[tid + 256] = 0.f;
        if (tid == 0) maxSlot = 0;
        if (j < 16) {
            int node = strip0 + j;
            bIds[wv * 16 + j] = (node < N_NODES) ? batch[node] : -1;
        }
    }

    // rowptr strip (17 values) in one vector load; broadcast via readlane
    const int rpv = rowptr[min(strip0 + min(j, 16), N_NODES)];
    const int sliceStart = __builtin_amdgcn_readlane(rpv, 0);
    const int sliceEnd = __builtin_amdgcn_readlane(rpv, 16);
    const int sliceLen = sliceEnd - sliceStart;

    for (int i = j; i < sliceLen && i < SCHUNK; i += 64)
        ldsSrc[wv][i] = __builtin_nontemporal_load(&srcList[sliceStart + i]);

    _Float16* aggH = scratch[wv];
    _Float16* aggL = scratch[wv] + 1152;

#define GISSUE(K, TMP, CNT, R0LOC, EB)                                                \
    half4v TMP = {0, 0, 0, 0};                                                        \
    if ((K) < ((min((CNT) - (EB), 32) + 3) >> 2)) {                                   \
        int e_ = (EB) + 4 * (K) + eoff;                                               \
        int ec_ = min(e_, (CNT)-1);                                                   \
        int idx_ = (R0LOC) + ec_;                                                     \
        int id_ = (idx_ < SCHUNK) ? ldsSrc[wv][idx_]                                  \
                                  : __builtin_nontemporal_load(&srcList[sliceStart + idx_]); \
        TMP = *(const half4v*)(in + (size_t)id_ * 64 + lf * 4);                       \
    }
#define GCONS(K, TMP, CNT, EB, A)                                                     \
    if ((EB) + 4 * (K) + eoff < (CNT)) {                                              \
        A[0] += (float)TMP.x; A[1] += (float)TMP.y;                                   \
        A[2] += (float)TMP.z; A[3] += (float)TMP.w;                                   \
    }

    for (int mp = 0; mp < 8; ++mp) {
        const int mA = 2 * mp, mB = mA + 1;
        const int nodeA = strip0 + mA, nodeB = strip0 + mB;
        const int r0A = __builtin_amdgcn_readlane(rpv, mA);
        const int r1A = __builtin_amdgcn_readlane(rpv, mA + 1);
        const int r1B = __builtin_amdgcn_readlane(rpv, mB + 1);
        const int cntA = (nodeA < N_NODES) ? r1A - r0A : 0;
        const int cntB = (nodeB < N_NODES) ? r1B - r1A : 0;
        const int locA = r0A - sliceStart, locB = r1A - sliceStart;

        float aA[4] = {0.f, 0.f, 0.f, 0.f}, aB[4] = {0.f, 0.f, 0.f, 0.f};

        // self terms (group 0 lanes only -> counted once after the group reduction)
        half4v sA = {0, 0, 0, 0}, sB = {0, 0, 0, 0};
        if (eoff == 0) {
            if (nodeA < N_NODES) sA = *(const half4v*)(in + (size_t)nodeA * 64 + lf * 4);
            if (nodeB < N_NODES) sB = *(const half4v*)(in + (size_t)nodeB * 64 + lf * 4);
        }

        // batched issue: first 32 edges of BOTH rows in flight before any consume
        {
            GISSUE(0, vA0, cntA, locA, 0) GISSUE(1, vA1, cntA, locA, 0)
            GISSUE(2, vA2, cntA, locA, 0) GISSUE(3, vA3, cntA, locA, 0)
            GISSUE(4, vA4, cntA, locA, 0) GISSUE(5, vA5, cntA, locA, 0)
            GISSUE(6, vA6, cntA, locA, 0) GISSUE(7, vA7, cntA, locA, 0)
            GISSUE(0, vB0, cntB, locB, 0) GISSUE(1, vB1, cntB, locB, 0)
            GISSUE(2, vB2, cntB, locB, 0) GISSUE(3, vB3, cntB, locB, 0)
            GISSUE(4, vB4, cntB, locB, 0) GISSUE(5, vB5, cntB, locB, 0)
            GISSUE(6, vB6, cntB, locB, 0) GISSUE(7, vB7, cntB, locB, 0)
            GCONS(0, vA0, cntA, 0, aA) GCONS(1, vA1, cntA, 0, aA)
            GCONS(2, vA2, cntA, 0, aA) GCONS(3, vA3, cntA, 0, aA)
            GCONS(4, vA4, cntA, 0, aA) GCONS(5, vA5, cntA, 0, aA)
            GCONS(6, vA6, cntA, 0, aA) GCONS(7, vA7, cntA, 0, aA)
            GCONS(0, vB0, cntB, 0, aB) GCONS(1, vB1, cntB, 0, aB)
            GCONS(2, vB2, cntB, 0, aB) GCONS(3, vB3, cntB, 0, aB)
            GCONS(4, vB4, cntB, 0, aB) GCONS(5, vB5, cntB, 0, aB)
            GCONS(6, vB6, cntB, 0, aB) GCONS(7, vB7, cntB, 0, aB)
        }
        // rare tails (> 32 edges per row)
        for (int eb = 32; eb < cntA; eb += 32) {
            GISSUE(0, w0, cntA, locA, eb) GISSUE(1, w1, cntA, locA, eb)
            GISSUE(2, w2, cntA, locA, eb) GISSUE(3, w3, cntA, locA, eb)
            GISSUE(4, w4, cntA, locA, eb) GISSUE(5, w5, cntA, locA, eb)
            GISSUE(6, w6, cntA, locA, eb) GISSUE(7, w7, cntA, locA, eb)
            GCONS(0, w0, cntA, eb, aA) GCONS(1, w1, cntA, eb, aA)
            GCONS(2, w2, cntA, eb, aA) GCONS(3, w3, cntA, eb, aA)
            GCONS(4, w4, cntA, eb, aA) GCONS(5, w5, cntA, eb, aA)
            GCONS(6, w6, cntA, eb, aA) GCONS(7, w7, cntA, eb, aA)
        }
        for (int eb = 32; eb < cntB; eb += 32) {
            GISSUE(0, w0, cntB, locB, eb) GISSUE(1, w1, cntB, locB, eb)
            GISSUE(2, w2, cntB, locB, eb) GISSUE(3, w3, cntB, locB, eb)
            GISSUE(4, w4, cntB, locB, eb) GISSUE(5, w5, cntB, locB, eb)
            GISSUE(6, w6, cntB, locB, eb) GISSUE(7, w7, cntB, locB, eb)
            GCONS(0, w0, cntB, eb, aB) GCONS(1, w1, cntB, eb, aB)
            GCONS(2, w2, cntB, eb, aB) GCONS(3, w3, cntB, eb, aB)
            GCONS(4, w4, cntB, eb, aB) GCONS(5, w5, cntB, eb, aB)
            GCONS(6, w6, cntB, eb, aB) GCONS(7, w7, cntB, eb, aB)
        }
        // add self (group 0 only), reduce 4 edge-groups, split hi/lo, store to LDS
        if (eoff == 0) {
            aA[0] += (float)sA.x; aA[1] += (float)sA.y; aA[2] += (float)sA.z; aA[3] += (float)sA.w;
            aB[0] += (float)sB.x; aB[1] += (float)sB.y; aB[2] += (float)sB.z; aB[3] += (float)sB.w;
        }
#pragma unroll
        for (int i = 0; i < 4; ++i) {
            aA[i] += __shfl_xor(aA[i], 16, 64);
            aA[i] += __shfl_xor(aA[i], 32, 64);
            aB[i] += __shfl_xor(aB[i], 16, 64);
            aB[i] += __shfl_xor(aB[i], 32, 64);
        }
        if (j < 16) {
            half4v hiA, loA, hiB, loB;
#pragma unroll
            for (int i = 0; i < 4; ++i) {
                hiA[i] = (_Float16)aA[i]; loA[i] = (_Float16)(aA[i] - (float)hiA[i]);
                hiB[i] = (_Float16)aB[i]; loB[i] = (_Float16)(aB[i] - (float)hiB[i]);
            }
            *(half4v*)(aggH + mA * 72 + 4 * j) = hiA;
            *(half4v*)(aggL + mA * 72 + 4 * j) = loA;
            *(half4v*)(aggH + mB * 72 + 4 * j) = hiB;
            *(half4v*)(aggL + mB * 72 + 4 * j) = loB;
        }
    }
#undef GISSUE
#undef GCONS

    const int l15 = j & 15, quad = j >> 4;
    const floatx4 vzero = {0.f, 0.f, 0.f, 0.f};

    // ---- linear1 (+BN fold) ----  (A rows are wave-private: no barrier needed)
    floatx4 acc[4] = {vzero, vzero, vzero, vzero};
    {
        const _Float16* aH0 = aggH + l15 * 72 + quad * 8;
        const _Float16* aL0 = aggL + l15 * 72 + quad * 8;
#pragma unroll
        for (int k0 = 0; k0 < 2; ++k0) {
            half8 aH = *(const half8*)(aH0 + k0 * 32);
            half8 aL = *(const half8*)(aL0 + k0 * 32);
#pragma unroll
            for (int c = 0; c < 4; ++c) {
                const int fo = ((k0 * 4 + c) * 64 + j) * 8;
                half8 bH = *(const half8*)(wH1 + fo);
                half8 bL = *(const half8*)(wL1 + fo);
                acc[c] = __builtin_amdgcn_mfma_f32_16x16x32_f16(aH, bH, acc[c], 0, 0, 0);
                acc[c] = __builtin_amdgcn_mfma_f32_16x16x32_f16(aL, bH, acc[c], 0, 0, 0);
                acc[c] = __builtin_amdgcn_mfma_f32_16x16x32_f16(aH, bL, acc[c], 0, 0, 0);
            }
        }
    }
    _Float16* hH = aggH;
    _Float16* hL = aggL;
#pragma unroll
    for (int c = 0; c < 4; ++c) {
        const float bv = b1[c * 16 + l15];
#pragma unroll
        for (int r = 0; r < 4; ++r) {
            const int row = quad * 4 + r, col = c * 16 + l15;
            float v = acc[c][r] + bv;
            v = fmaxf(v, 0.f);
            const _Float16 hi = (_Float16)v;
            hH[row * 72 + col] = hi;
            hL[row * 72 + col] = (_Float16)(v - (float)hi);
        }
    }

    // ---- linear2 ----
    floatx4 acc2[4] = {vzero, vzero, vzero, vzero};
    {
        const _Float16* aH0 = hH + l15 * 72 + quad * 8;
        const _Float16* aL0 = hL + l15 * 72 + quad * 8;
#pragma unroll
        for (int k0 = 0; k0 < 2; ++k0) {
            half8 aH = *(const half8*)(aH0 + k0 * 32);
            half8 aL = *(const half8*)(aL0 + k0 * 32);
#pragma unroll
            for (int c = 0; c < 4; ++c) {
                const int fo = ((k0 * 4 + c) * 64 + j) * 8;
                half8 bH = *(const half8*)(wH2 + fo);
                half8 bL = *(const half8*)(wL2 + fo);
                acc2[c] = __builtin_amdgcn_mfma_f32_16x16x32_f16(aH, bH, acc2[c], 0, 0, 0);
                acc2[c] = __builtin_amdgcn_mfma_f32_16x16x32_f16(aL, bH, acc2[c], 0, 0, 0);
                acc2[c] = __builtin_amdgcn_mfma_f32_16x16x32_f16(aH, bL, acc2[c], 0, 0, 0);
            }
        }
    }

    // ---- epilogue ----
    if (!POOL) {
#pragma unroll
        for (int c = 0; c < 4; ++c) {
            const float bv = b2[c * 16 + l15];
#pragma unroll
            for (int r = 0; r < 4; ++r) {
                const int node = strip0 + quad * 4 + r;
                if (node < N_NODES)
                    __builtin_nontemporal_store((_Float16)fmaxf(acc2[c][r] + bv, 0.f),
                                                &out[(size_t)node * 64 + c * 16 + l15]);
            }
        }
    } else {
        float* oT = (float*)scratch[wv];  // 16 x 66, wave-private (H reads done)
#pragma unroll
        for (int c = 0; c < 4; ++c) {
            const float bv = b2[c * 16 + l15];
#pragma unroll
            for (int r = 0; r < 4; ++r)
                oT[(quad * 4 + r) * 66 + c * 16 + l15] = acc2[c][r] + bv;
        }
        __syncthreads();
        const int b0 = bIds[0];
        int curB = -1;
        float accv = 0.f;
        for (int r = 0; r < 16; ++r) {
            const int b = bIds[wv * 16 + r];  // wave-uniform
            if (b < 0) break;
            const float v = oT[r * 66 + j];
            if (b != curB) {
                if (curB >= 0) {
                    const int s = curB - b0;
                    if (s >= 0 && s < 8) {
                        atomicAdd(&pooledLoc[s * 64 + j], accv);
                        if (j == 0) atomicMax(&maxSlot, s);
                    } else {
                        atomicAdd(&pooled[curB * 64 + j], accv);
                    }
                }
                curB = b;
                accv = v;
            } else {
                accv += v;
            }
        }
        if (curB >= 0) {
            const int s = curB - b0;
            if (s >= 0 && s < 8) {
                atomicAdd(&pooledLoc[s * 64 + j], accv);
                if (j == 0) atomicMax(&maxSlot, s);
            } else {
                atomicAdd(&pooled[curB * 64 + j], accv);
            }
        }
        __syncthreads();
        if (b0 >= 0) {
            const int ns = maxSlot + 1;
            for (int s = wv; s < ns; s += 4)
                atomicAdd(&pooled[(b0 + s) * 64 + j], pooledLoc[s * 64 + j]);
        }

        // ---- fused classifier: last block finishes the pipeline ----
        __threadfence();
        if (tid == 0) amLast = (atomicAdd(doneCnt, 1) == (int)gridDim.x - 1) ? 1 : 0;
        __syncthreads();
        if (amLast) {
            for (int g = tid; g < N_GRAPHS; g += 256) {
                const float cg = fmaxf((float)(gstart[g + 1] - gstart[g]), 1.f);
                float o[N_CLS];
#pragma unroll
                for (int c = 0; c < N_CLS; ++c) o[c] = 0.f;
                for (int k = 0; k < 64; ++k) {
                    const float pv = atomicAdd(&pooled[g * 64 + k], 0.f);  // coherent read
#pragma unroll
                    for (int c = 0; c < N_CLS; ++c) o[c] = fmaf(pv, wc[k * N_CLS + c], o[c]);
                }
#pragma unroll
                for (int c = 0; c < N_CLS; ++c) outF[g * N_CLS + c] = o[c] / cg + bc[c];
            }
        }
    }
}

// ---------------------------------------------------------------- launch

extern "C" void kernel_launch(void* const* d_in, const int* in_sizes, int n_in,
                              void* d_out, int out_size, void* d_ws, size_t ws_size,
                              hipStream_t stream) {
    const float* x   = (const float*)d_in[0];
    const int*   ei  = (const int*)d_in[1];
    const int* batch = (const int*)d_in[2];
    const float* w0a = (const float*)d_in[3];
    const float* b0a = (const float*)d_in[4];
    const float* g0  = (const float*)d_in[5];
    const float* be0 = (const float*)d_in[6];
    const float* m0  = (const float*)d_in[7];
    const float* v0  = (const float*)d_in[8];
    const float* w0b = (const float*)d_in[9];
    const float* b0b = (const float*)d_in[10];
    const float* w1a = (const float*)d_in[11];
    const float* b1a = (const float*)d_in[12];
    const float* g1  = (const float*)d_in[13];
    const float* be1 = (const float*)d_in[14];
    const float* m1  = (const float*)d_in[15];
    const float* v1  = (const float*)d_in[16];
    const float* w1b = (const float*)d_in[17];
    const float* b1b = (const float*)d_in[18];
    const float* wc  = (const float*)d_in[19];
    const float* bc  = (const float*)d_in[20];
    float* out = (float*)d_out;

    const int* srcI = ei;
    const int* dstI = ei + N_EDGES;

    // workspace layout, offsets in 4-byte units
    int* ws = (int*)d_ws;
    int*      deg       = ws;                              // 100000
    unsigned long long* status = (unsigned long long*)(ws + 100000);  // 200 u64 = 400 ints
    int*      doneCnt   = ws + 100400;                     // 4
    float*    pooled    = (float*)(ws + 100404);           // 32768  (memset covers 0..133172)
    int*      rowptr    = ws + 133172;                     // 100001
    int*      rank      = ws + 233176;                     // 1000000
    int*      sortedSrc = ws + 1233176;                    // 1000000
    _Float16* xh        = (_Float16*)(ws + 2233176);       // 6400000 halves
    _Float16* h1        = (_Float16*)(ws + 5433176);       // 6400000 halves
    float*    b1p0      = (float*)(ws + 8633176);          // 64
    float*    b1p1      = (float*)(ws + 8633240);          // 64
    int*      gstart    = ws + 8633304;                    // 513
    _Float16* wHi       = (_Float16*)(ws + 8633820);       // 16384 halves
    _Float16* wLo       = (_Float16*)(ws + 8642012);       // 16384 halves

    // zero deg+status+doneCnt+pooled in one async memset (graph-capture-safe)
    hipMemsetAsync((void*)deg, 0, 133172 * sizeof(int), stream);
    prep_kernel<<<6250, 256, 0, stream>>>(x, xh, batch, dstI, deg, rank,
                                          w0a, b0a, g0, be0, m0, v0, w0b,
                                          w1a, b1a, g1, be1, m1, v1, w1b,
                                          gstart, wHi, wLo, b1p0, b1p1);

    scan_lb_kernel<<<LB_NB, 256, 0, stream>>>(deg, status, rowptr);
    fill_kernel<<<(N_EDGES + 255) / 256, 256, 0, stream>>>(srcI, dstI, rank, rowptr, sortedSrc);

    // conv0: h1 = relu(mlp0(x + gather(x)))   [fp16 features]
    conv_mfma<0><<<NTILES, 256, 0, stream>>>(xh, rowptr, sortedSrc,
                                             wHi, wLo, wHi + 4096, wLo + 4096,
                                             b1p0, b0b, h1, nullptr, nullptr,
                                             nullptr, nullptr, nullptr, nullptr, nullptr);

    // conv1: pooled += mlp1(h1 + gather(h1)); last block runs classifier
    conv_mfma<1><<<NTILES, 256, 0, stream>>>(h1, rowptr, sortedSrc,
                                             wHi + 8192, wLo + 8192, wHi + 12288, wLo + 12288,
                                             b1p1, b1b, nullptr, batch, pooled,
                                             wc, bc, gstart, doneCnt, out);
}

// Round 8
// 446.541 us; speedup vs baseline: 1.0056x; 1.0056x over previous
//
#include <hip/hip_runtime.h>

#define N_NODES 100000
#define N_EDGES 1000000
#define N_GRAPHS 512
#define N_CLS 10
#define BN_EPS 1e-5f

#define LB_NB 200     // lookback-scan blocks (200*512 >= 100000); all co-resident
#define NTILES 1563   // ceil(100000/64)
#define SCHUNK 320    // per-wave staged src ids (strip slice ~Poisson(160))

typedef _Float16 half8 __attribute__((ext_vector_type(8)));
typedef _Float16 half4v __attribute__((ext_vector_type(4)));
typedef float floatx4 __attribute__((ext_vector_type(4)));

// ---------------------------------------------------------------- prep
__global__ __launch_bounds__(256) void prep_kernel(
    const float* __restrict__ x, _Float16* __restrict__ xh,
    const int* __restrict__ batch, const int* __restrict__ dstI,
    int* __restrict__ deg, int* __restrict__ rank,
    const float* __restrict__ w0a, const float* __restrict__ b0a,
    const float* __restrict__ g0, const float* __restrict__ be0,
    const float* __restrict__ m0, const float* __restrict__ v0,
    const float* __restrict__ w0b,
    const float* __restrict__ w1a, const float* __restrict__ b1a,
    const float* __restrict__ g1, const float* __restrict__ be1,
    const float* __restrict__ m1, const float* __restrict__ v1,
    const float* __restrict__ w1b,
    int* __restrict__ gstart,
    _Float16* __restrict__ wHi, _Float16* __restrict__ wLo,
    float* __restrict__ b1p0, float* __restrict__ b1p1) {
    const int gid = blockIdx.x * 256 + threadIdx.x;

    if (gid < 1600000) {  // x -> fp16 (6.4M elems as float4 -> half4)
        float4 v = ((const float4*)x)[gid];
        half4v h = {(_Float16)v.x, (_Float16)v.y, (_Float16)v.z, (_Float16)v.w};
        ((half4v*)xh)[gid] = h;
    }

    if (gid < N_EDGES)  // histogram + per-edge rank within dst bucket
        rank[gid] = atomicAdd(&deg[dstI[gid]], 1);

    if (gid <= N_NODES) {  // graph boundaries from sorted batch
        int bcur = (gid < N_NODES) ? batch[gid] : N_GRAPHS;
        int bprev = (gid > 0) ? batch[gid - 1] : -1;
        for (int g = bprev + 1; g <= bcur; ++g) gstart[g] = gid;
    }

    if (gid < 16384) {  // W frag pack: [mat(4)][k0(2)][c(4)][lane(64)][jj(8)]
        const int e = gid & 4095, mat = gid >> 12;
        const int jj = e & 7, lane = (e >> 3) & 63, c = (e >> 9) & 3, k0 = (e >> 11) & 1;
        const int k = k0 * 32 + (lane >> 4) * 8 + jj;
        const int col = c * 16 + (lane & 15);
        float val;
        if (mat == 0)      val = w0a[k * 64 + col] * (rsqrtf(v0[col] + BN_EPS) * g0[col]);
        else if (mat == 1) val = w0b[k * 64 + col];
        else if (mat == 2) val = w1a[k * 64 + col] * (rsqrtf(v1[col] + BN_EPS) * g1[col]);
        else               val = w1b[k * 64 + col];
        _Float16 hi = (_Float16)val;
        wHi[gid] = hi;
        wLo[gid] = (_Float16)(val - (float)hi);
    }

    if (gid >= 16384 && gid < 16512) {  // BN-folded biases
        int t = gid - 16384;
        if (t < 64) {
            float s = rsqrtf(v0[t] + BN_EPS) * g0[t];
            b1p0[t] = (b0a[t] - m0[t]) * s + be0[t];
        } else {
            t -= 64;
            float s = rsqrtf(v1[t] + BN_EPS) * g1[t];
            b1p1[t] = (b1a[t] - m1[t]) * s + be1[t];
        }
    }
}

// ---------------------------------------------------------------- single-pass scan
__global__ __launch_bounds__(256) void scan_lb_kernel(const int* __restrict__ deg,
                                                      unsigned long long* __restrict__ status,
                                                      int* __restrict__ rowptr) {
    __shared__ int sh[256];
    __shared__ int sbase;
    const int blk = blockIdx.x;
    const int t = threadIdx.x;
    const int i0 = blk * 512 + 2 * t, i1 = i0 + 1;
    const int d0 = (i0 < N_NODES) ? deg[i0] : 0;
    const int d1 = (i1 < N_NODES) ? deg[i1] : 0;
    const int p = d0 + d1;
    sh[t] = p;
    __syncthreads();
#pragma unroll
    for (int off = 1; off < 256; off <<= 1) {
        int u = (t >= off) ? sh[t - off] : 0;
        __syncthreads();
        sh[t] += u;
        __syncthreads();
    }
    const int agg = sh[255];
    if (t == 0) {
        if (blk == 0) {
            atomicExch(&status[0], (2ULL << 32) | (unsigned)agg);
            sbase = 0;
        } else {
            atomicExch(&status[blk], (1ULL << 32) | (unsigned)agg);
            int base = 0;
            int jb = blk - 1;
            while (jb >= 0) {
                unsigned long long s;
                do { s = atomicAdd(&status[jb], 0ULL); } while ((s >> 32) == 0);
                base += (int)(unsigned)s;
                if ((s >> 32) == 2ULL) break;
                --jb;
            }
            atomicExch(&status[blk], (2ULL << 32) | (unsigned)(base + agg));
            sbase = base;
        }
    }
    __syncthreads();
    const int excl = sbase + sh[t] - p;
    if (i0 < N_NODES) rowptr[i0] = excl;
    if (i1 < N_NODES) rowptr[i1] = excl + d0;
    if (blk == LB_NB - 1 && t == 255) rowptr[N_NODES] = N_EDGES;
}

__global__ __launch_bounds__(256) void fill_kernel(const int* __restrict__ srcI,
                                                   const int* __restrict__ dstI,
                                                   const int* __restrict__ rank,
                                                   const int* __restrict__ rowptr,
                                                   int* __restrict__ sortedSrc) {
    int e = blockIdx.x * 256 + threadIdx.x;
    if (e >= N_EDGES) return;
    sortedSrc[rowptr[dstI[e]] + rank[e]] = srcI[e];
}

// ---------------------------------------------------------------- fused conv (MFMA, fp16)
// Gather: lane = (edge-subindex j>>4, feature-chunk j&15), half4/lane -> 4 full
// 128B rows per wave instruction; ids per-lane from LDS-staged CSR slice.
// NOTE: h1 and gather-table reads/writes use PLAIN loads/stores — the gather
// table must stay L2/L3-resident (R7's nontemporal h1 store caused a 2.3x
// regression by forcing conv1's random reads to HBM).
template <int POOL>
__global__ __launch_bounds__(256) void conv_mfma(
    const _Float16* __restrict__ in, const int* __restrict__ rowptr,
    const int* __restrict__ srcList,
    const _Float16* __restrict__ wH1, const _Float16* __restrict__ wL1,
    const _Float16* __restrict__ wH2, const _Float16* __restrict__ wL2,
    const float* __restrict__ b1, const float* __restrict__ b2,
    _Float16* __restrict__ out, const int* __restrict__ batch,
    float* __restrict__ pooled,
    const float* __restrict__ wc, const float* __restrict__ bc,
    const int* __restrict__ gstart, int* __restrict__ doneCnt,
    float* __restrict__ outF) {
    __shared__ __align__(16) _Float16 scratch[4][2304];  // per-wave aggH|aggL -> hH|hL -> oT
    __shared__ int ldsSrc[4][SCHUNK];
    __shared__ float pooledLoc[8 * 64];
    __shared__ int bIds[64];
    __shared__ int maxSlot;
    __shared__ int amLast;

    const int tid = threadIdx.x;
    const int j = tid & 63, wv = tid >> 6;
    const int eoff = j >> 4;    // edge sub-index within a 4-edge load group
    const int lf = j & 15;      // feature chunk (4 features)
    const int base = blockIdx.x * 64;
    const int strip0 = base + wv * 16;

    if (POOL) {
        pooledLoc[tid] = 0.f;
        pooledLoc[tid + 256] = 0.f;
        if (tid == 0) maxSlot = 0;
        if (j < 16) {
            int node = strip0 + j;
            bIds[wv * 16 + j] = (node < N_NODES) ? batch[node] : -1;
        }
    }

    // rowptr strip (17 values) in one vector load; broadcast via readlane
    const int rpv = rowptr[min(strip0 + min(j, 16), N_NODES)];
    const int sliceStart = __builtin_amdgcn_readlane(rpv, 0);
    const int sliceEnd = __builtin_amdgcn_readlane(rpv, 16);
    const int sliceLen = sliceEnd - sliceStart;

    for (int i = j; i < sliceLen && i < SCHUNK; i += 64)
        ldsSrc[wv][i] = srcList[sliceStart + i];

    _Float16* aggH = scratch[wv];
    _Float16* aggL = scratch[wv] + 1152;

#define GISSUE(K, TMP, CNT, R0LOC, EB)                                                \
    half4v TMP = {0, 0, 0, 0};                                                        \
    if ((K) < ((min((CNT) - (EB), 32) + 3) >> 2)) {                                   \
        int e_ = (EB) + 4 * (K) + eoff;                                               \
        int ec_ = min(e_, (CNT)-1);                                                   \
        int idx_ = (R0LOC) + ec_;                                                     \
        int id_ = (idx_ < SCHUNK) ? ldsSrc[wv][idx_] : srcList[sliceStart + idx_];    \
        TMP = *(const half4v*)(in + (size_t)id_ * 64 + lf * 4);                       \
    }
#define GCONS(K, TMP, CNT, EB, A)                                                     \
    if ((EB) + 4 * (K) + eoff < (CNT)) {                                              \
        A[0] += (float)TMP.x; A[1] += (float)TMP.y;                                   \
        A[2] += (float)TMP.z; A[3] += (float)TMP.w;                                   \
    }

    for (int mp = 0; mp < 8; ++mp) {
        const int mA = 2 * mp, mB = mA + 1;
        const int nodeA = strip0 + mA, nodeB = strip0 + mB;
        const int r0A = __builtin_amdgcn_readlane(rpv, mA);
        const int r1A = __builtin_amdgcn_readlane(rpv, mA + 1);
        const int r1B = __builtin_amdgcn_readlane(rpv, mB + 1);
        const int cntA = (nodeA < N_NODES) ? r1A - r0A : 0;
        const int cntB = (nodeB < N_NODES) ? r1B - r1A : 0;
        const int locA = r0A - sliceStart, locB = r1A - sliceStart;

        float aA[4] = {0.f, 0.f, 0.f, 0.f}, aB[4] = {0.f, 0.f, 0.f, 0.f};

        half4v sA = {0, 0, 0, 0}, sB = {0, 0, 0, 0};
        if (eoff == 0) {
            if (nodeA < N_NODES) sA = *(const half4v*)(in + (size_t)nodeA * 64 + lf * 4);
            if (nodeB < N_NODES) sB = *(const half4v*)(in + (size_t)nodeB * 64 + lf * 4);
        }

        // batched issue: first 32 edges of BOTH rows in flight before any consume
        {
            GISSUE(0, vA0, cntA, locA, 0) GISSUE(1, vA1, cntA, locA, 0)
            GISSUE(2, vA2, cntA, locA, 0) GISSUE(3, vA3, cntA, locA, 0)
            GISSUE(4, vA4, cntA, locA, 0) GISSUE(5, vA5, cntA, locA, 0)
            GISSUE(6, vA6, cntA, locA, 0) GISSUE(7, vA7, cntA, locA, 0)
            GISSUE(0, vB0, cntB, locB, 0) GISSUE(1, vB1, cntB, locB, 0)
            GISSUE(2, vB2, cntB, locB, 0) GISSUE(3, vB3, cntB, locB, 0)
            GISSUE(4, vB4, cntB, locB, 0) GISSUE(5, vB5, cntB, locB, 0)
            GISSUE(6, vB6, cntB, locB, 0) GISSUE(7, vB7, cntB, locB, 0)
            GCONS(0, vA0, cntA, 0, aA) GCONS(1, vA1, cntA, 0, aA)
            GCONS(2, vA2, cntA, 0, aA) GCONS(3, vA3, cntA, 0, aA)
            GCONS(4, vA4, cntA, 0, aA) GCONS(5, vA5, cntA, 0, aA)
            GCONS(6, vA6, cntA, 0, aA) GCONS(7, vA7, cntA, 0, aA)
            GCONS(0, vB0, cntB, 0, aB) GCONS(1, vB1, cntB, 0, aB)
            GCONS(2, vB2, cntB, 0, aB) GCONS(3, vB3, cntB, 0, aB)
            GCONS(4, vB4, cntB, 0, aB) GCONS(5, vB5, cntB, 0, aB)
            GCONS(6, vB6, cntB, 0, aB) GCONS(7, vB7, cntB, 0, aB)
        }
        // rare tails (> 32 edges per row)
        for (int eb = 32; eb < cntA; eb += 32) {
            GISSUE(0, w0, cntA, locA, eb) GISSUE(1, w1, cntA, locA, eb)
            GISSUE(2, w2, cntA, locA, eb) GISSUE(3, w3, cntA, locA, eb)
            GISSUE(4, w4, cntA, locA, eb) GISSUE(5, w5, cntA, locA, eb)
            GISSUE(6, w6, cntA, locA, eb) GISSUE(7, w7, cntA, locA, eb)
            GCONS(0, w0, cntA, eb, aA) GCONS(1, w1, cntA, eb, aA)
            GCONS(2, w2, cntA, eb, aA) GCONS(3, w3, cntA, eb, aA)
            GCONS(4, w4, cntA, eb, aA) GCONS(5, w5, cntA, eb, aA)
            GCONS(6, w6, cntA, eb, aA) GCONS(7, w7, cntA, eb, aA)
        }
        for (int eb = 32; eb < cntB; eb += 32) {
            GISSUE(0, w0, cntB, locB, eb) GISSUE(1, w1, cntB, locB, eb)
            GISSUE(2, w2, cntB, locB, eb) GISSUE(3, w3, cntB, locB, eb)
            GISSUE(4, w4, cntB, locB, eb) GISSUE(5, w5, cntB, locB, eb)
            GISSUE(6, w6, cntB, locB, eb) GISSUE(7, w7, cntB, locB, eb)
            GCONS(0, w0, cntB, eb, aB) GCONS(1, w1, cntB, eb, aB)
            GCONS(2, w2, cntB, eb, aB) GCONS(3, w3, cntB, eb, aB)
            GCONS(4, w4, cntB, eb, aB) GCONS(5, w5, cntB, eb, aB)
            GCONS(6, w6, cntB, eb, aB) GCONS(7, w7, cntB, eb, aB)
        }
        if (eoff == 0) {
            aA[0] += (float)sA.x; aA[1] += (float)sA.y; aA[2] += (float)sA.z; aA[3] += (float)sA.w;
            aB[0] += (float)sB.x; aB[1] += (float)sB.y; aB[2] += (float)sB.z; aB[3] += (float)sB.w;
        }
#pragma unroll
        for (int i = 0; i < 4; ++i) {
            aA[i] += __shfl_xor(aA[i], 16, 64);
            aA[i] += __shfl_xor(aA[i], 32, 64);
            aB[i] += __shfl_xor(aB[i], 16, 64);
            aB[i] += __shfl_xor(aB[i], 32, 64);
        }
        if (j < 16) {
            half4v hiA, loA, hiB, loB;
#pragma unroll
            for (int i = 0; i < 4; ++i) {
                hiA[i] = (_Float16)aA[i]; loA[i] = (_Float16)(aA[i] - (float)hiA[i]);
                hiB[i] = (_Float16)aB[i]; loB[i] = (_Float16)(aB[i] - (float)hiB[i]);
            }
            *(half4v*)(aggH + mA * 72 + 4 * j) = hiA;
            *(half4v*)(aggL + mA * 72 + 4 * j) = loA;
            *(half4v*)(aggH + mB * 72 + 4 * j) = hiB;
            *(half4v*)(aggL + mB * 72 + 4 * j) = loB;
        }
    }
#undef GISSUE
#undef GCONS

    const int l15 = j & 15, quad = j >> 4;
    const floatx4 vzero = {0.f, 0.f, 0.f, 0.f};

    // ---- linear1 (+BN fold) ----
    floatx4 acc[4] = {vzero, vzero, vzero, vzero};
    {
        const _Float16* aH0 = aggH + l15 * 72 + quad * 8;
        const _Float16* aL0 = aggL + l15 * 72 + quad * 8;
#pragma unroll
        for (int k0 = 0; k0 < 2; ++k0) {
            half8 aH = *(const half8*)(aH0 + k0 * 32);
            half8 aL = *(const half8*)(aL0 + k0 * 32);
#pragma unroll
            for (int c = 0; c < 4; ++c) {
                const int fo = ((k0 * 4 + c) * 64 + j) * 8;
                half8 bH = *(const half8*)(wH1 + fo);
                half8 bL = *(const half8*)(wL1 + fo);
                acc[c] = __builtin_amdgcn_mfma_f32_16x16x32_f16(aH, bH, acc[c], 0, 0, 0);
                acc[c] = __builtin_amdgcn_mfma_f32_16x16x32_f16(aL, bH, acc[c], 0, 0, 0);
                acc[c] = __builtin_amdgcn_mfma_f32_16x16x32_f16(aH, bL, acc[c], 0, 0, 0);
            }
        }
    }
    _Float16* hH = aggH;
    _Float16* hL = aggL;
#pragma unroll
    for (int c = 0; c < 4; ++c) {
        const float bv = b1[c * 16 + l15];
#pragma unroll
        for (int r = 0; r < 4; ++r) {
            const int row = quad * 4 + r, col = c * 16 + l15;
            float v = acc[c][r] + bv;
            v = fmaxf(v, 0.f);
            const _Float16 hi = (_Float16)v;
            hH[row * 72 + col] = hi;
            hL[row * 72 + col] = (_Float16)(v - (float)hi);
        }
    }

    // ---- linear2 ----
    floatx4 acc2[4] = {vzero, vzero, vzero, vzero};
    {
        const _Float16* aH0 = hH + l15 * 72 + quad * 8;
        const _Float16* aL0 = hL + l15 * 72 + quad * 8;
#pragma unroll
        for (int k0 = 0; k0 < 2; ++k0) {
            half8 aH = *(const half8*)(aH0 + k0 * 32);
            half8 aL = *(const half8*)(aL0 + k0 * 32);
#pragma unroll
            for (int c = 0; c < 4; ++c) {
                const int fo = ((k0 * 4 + c) * 64 + j) * 8;
                half8 bH = *(const half8*)(wH2 + fo);
                half8 bL = *(const half8*)(wL2 + fo);
                acc2[c] = __builtin_amdgcn_mfma_f32_16x16x32_f16(aH, bH, acc2[c], 0, 0, 0);
                acc2[c] = __builtin_amdgcn_mfma_f32_16x16x32_f16(aL, bH, acc2[c], 0, 0, 0);
                acc2[c] = __builtin_amdgcn_mfma_f32_16x16x32_f16(aH, bL, acc2[c], 0, 0, 0);
            }
        }
    }

    // ---- epilogue ----
    if (!POOL) {
        // PLAIN stores: h1 must stay cache-resident for conv1's random gather
#pragma unroll
        for (int c = 0; c < 4; ++c) {
            const float bv = b2[c * 16 + l15];
#pragma unroll
            for (int r = 0; r < 4; ++r) {
                const int node = strip0 + quad * 4 + r;
                if (node < N_NODES)
                    out[(size_t)node * 64 + c * 16 + l15] =
                        (_Float16)fmaxf(acc2[c][r] + bv, 0.f);
            }
        }
    } else {
        float* oT = (float*)scratch[wv];  // 16 x 66, wave-private (H reads done)
#pragma unroll
        for (int c = 0; c < 4; ++c) {
            const float bv = b2[c * 16 + l15];
#pragma unroll
            for (int r = 0; r < 4; ++r)
                oT[(quad * 4 + r) * 66 + c * 16 + l15] = acc2[c][r] + bv;
        }
        __syncthreads();
        const int b0 = bIds[0];
        int curB = -1;
        float accv = 0.f;
        for (int r = 0; r < 16; ++r) {
            const int b = bIds[wv * 16 + r];  // wave-uniform
            if (b < 0) break;
            const float v = oT[r * 66 + j];
            if (b != curB) {
                if (curB >= 0) {
                    const int s = curB - b0;
                    if (s >= 0 && s < 8) {
                        atomicAdd(&pooledLoc[s * 64 + j], accv);
                        if (j == 0) atomicMax(&maxSlot, s);
                    } else {
                        atomicAdd(&pooled[curB * 64 + j], accv);
                    }
                }
                curB = b;
                accv = v;
            } else {
                accv += v;
            }
        }
        if (curB >= 0) {
            const int s = curB - b0;
            if (s >= 0 && s < 8) {
                atomicAdd(&pooledLoc[s * 64 + j], accv);
                if (j == 0) atomicMax(&maxSlot, s);
            } else {
                atomicAdd(&pooled[curB * 64 + j], accv);
            }
        }
        __syncthreads();
        if (b0 >= 0) {
            const int ns = maxSlot + 1;
            for (int s = wv; s < ns; s += 4)
                atomicAdd(&pooled[(b0 + s) * 64 + j], pooledLoc[s * 64 + j]);
        }

        // ---- fused classifier: last block finishes the pipeline ----
        __threadfence();
        if (tid == 0) amLast = (atomicAdd(doneCnt, 1) == (int)gridDim.x - 1) ? 1 : 0;
        __syncthreads();
        if (amLast) {
            for (int g = tid; g < N_GRAPHS; g += 256) {
                const float cg = fmaxf((float)(gstart[g + 1] - gstart[g]), 1.f);
                float o[N_CLS];
#pragma unroll
                for (int c = 0; c < N_CLS; ++c) o[c] = 0.f;
                for (int k = 0; k < 64; ++k) {
                    const float pv = atomicAdd(&pooled[g * 64 + k], 0.f);  // coherent read
#pragma unroll
                    for (int c = 0; c < N_CLS; ++c) o[c] = fmaf(pv, wc[k * N_CLS + c], o[c]);
                }
#pragma unroll
                for (int c = 0; c < N_CLS; ++c) outF[g * N_CLS + c] = o[c] / cg + bc[c];
            }
        }
    }
}

// ---------------------------------------------------------------- launch

extern "C" void kernel_launch(void* const* d_in, const int* in_sizes, int n_in,
                              void* d_out, int out_size, void* d_ws, size_t ws_size,
                              hipStream_t stream) {
    const float* x   = (const float*)d_in[0];
    const int*   ei  = (const int*)d_in[1];
    const int* batch = (const int*)d_in[2];
    const float* w0a = (const float*)d_in[3];
    const float* b0a = (const float*)d_in[4];
    const float* g0  = (const float*)d_in[5];
    const float* be0 = (const float*)d_in[6];
    const float* m0  = (const float*)d_in[7];
    const float* v0  = (const float*)d_in[8];
    const float* w0b = (const float*)d_in[9];
    const float* b0b = (const float*)d_in[10];
    const float* w1a = (const float*)d_in[11];
    const float* b1a = (const float*)d_in[12];
    const float* g1  = (const float*)d_in[13];
    const float* be1 = (const float*)d_in[14];
    const float* m1  = (const float*)d_in[15];
    const float* v1  = (const float*)d_in[16];
    const float* w1b = (const float*)d_in[17];
    const float* b1b = (const float*)d_in[18];
    const float* wc  = (const float*)d_in[19];
    const float* bc  = (const float*)d_in[20];
    float* out = (float*)d_out;

    const int* srcI = ei;
    const int* dstI = ei + N_EDGES;

    // workspace layout, offsets in 4-byte units
    int* ws = (int*)d_ws;
    int*      deg       = ws;                              // 100000
    unsigned long long* status = (unsigned long long*)(ws + 100000);  // 200 u64
    int*      doneCnt   = ws + 100400;                     // 4
    float*    pooled    = (float*)(ws + 100404);           // 32768
    int*      rowptr    = ws + 133172;                     // 100001
    int*      rank      = ws + 233176;                     // 1000000
    int*      sortedSrc = ws + 1233176;                    // 1000000
    _Float16* xh        = (_Float16*)(ws + 2233176);       // 6400000 halves
    _Float16* h1        = (_Float16*)(ws + 5433176);       // 6400000 halves
    float*    b1p0      = (float*)(ws + 8633176);          // 64
    float*    b1p1      = (float*)(ws + 8633240);          // 64
    int*      gstart    = ws + 8633304;                    // 513
    _Float16* wHi       = (_Float16*)(ws + 8633820);       // 16384 halves
    _Float16* wLo       = (_Float16*)(ws + 8642012);       // 16384 halves

    hipMemsetAsync((void*)deg, 0, 133172 * sizeof(int), stream);
    prep_kernel<<<6250, 256, 0, stream>>>(x, xh, batch, dstI, deg, rank,
                                          w0a, b0a, g0, be0, m0, v0, w0b,
                                          w1a, b1a, g1, be1, m1, v1, w1b,
                                          gstart, wHi, wLo, b1p0, b1p1);

    scan_lb_kernel<<<LB_NB, 256, 0, stream>>>(deg, status, rowptr);
    fill_kernel<<<(N_EDGES + 255) / 256, 256, 0, stream>>>(srcI, dstI, rank, rowptr, sortedSrc);

    // conv0: h1 = relu(mlp0(x + gather(x)))   [fp16 features]
    conv_mfma<0><<<NTILES, 256, 0, stream>>>(xh, rowptr, sortedSrc,
                                             wHi, wLo, wHi + 4096, wLo + 4096,
                                             b1p0, b0b, h1, nullptr, nullptr,
                                             nullptr, nullptr, nullptr, nullptr, nullptr);

    // conv1: pooled += mlp1(h1 + gather(h1)); last block runs classifier
    conv_mfma<1><<<NTILES, 256, 0, stream>>>(h1, rowptr, sortedSrc,
                                             wHi + 8192, wLo + 8192, wHi + 12288, wLo + 12288,
                                             b1p1, b1b, nullptr, batch, pooled,
                                             wc, bc, gstart, doneCnt, out);
}

// Round 9
// 309.040 us; speedup vs baseline: 1.4531x; 1.4449x over previous
//
#include <hip/hip_runtime.h>

#define N_NODES 100000
#define N_EDGES 1000000
#define N_GRAPHS 512
#define N_CLS 10
#define BN_EPS 1e-5f

#define LB_NB 200     // lookback-scan blocks (200*512 >= 100000); all co-resident
#define NTILES 1563   // ceil(100000/64)
#define SCHUNK 320    // per-wave staged src ids (strip slice ~Poisson(160))

typedef _Float16 half8 __attribute__((ext_vector_type(8)));
typedef _Float16 half4v __attribute__((ext_vector_type(4)));
typedef float floatx4 __attribute__((ext_vector_type(4)));

// ---------------------------------------------------------------- prep
__global__ __launch_bounds__(256) void prep_kernel(
    const float* __restrict__ x, _Float16* __restrict__ xh,
    const int* __restrict__ batch, const int* __restrict__ dstI,
    int* __restrict__ deg, int* __restrict__ rank,
    const float* __restrict__ w0a, const float* __restrict__ b0a,
    const float* __restrict__ g0, const float* __restrict__ be0,
    const float* __restrict__ m0, const float* __restrict__ v0,
    const float* __restrict__ w0b,
    const float* __restrict__ w1a, const float* __restrict__ b1a,
    const float* __restrict__ g1, const float* __restrict__ be1,
    const float* __restrict__ m1, const float* __restrict__ v1,
    const float* __restrict__ w1b,
    int* __restrict__ gstart,
    _Float16* __restrict__ wHi, _Float16* __restrict__ wLo,
    float* __restrict__ b1p0, float* __restrict__ b1p1) {
    const int gid = blockIdx.x * 256 + threadIdx.x;

    if (gid < 1600000) {  // x -> fp16 (6.4M elems as float4 -> half4)
        float4 v = ((const float4*)x)[gid];
        half4v h = {(_Float16)v.x, (_Float16)v.y, (_Float16)v.z, (_Float16)v.w};
        ((half4v*)xh)[gid] = h;
    }

    if (gid < N_EDGES)  // histogram + per-edge rank within dst bucket
        rank[gid] = atomicAdd(&deg[dstI[gid]], 1);

    if (gid <= N_NODES) {  // graph boundaries from sorted batch
        int bcur = (gid < N_NODES) ? batch[gid] : N_GRAPHS;
        int bprev = (gid > 0) ? batch[gid - 1] : -1;
        for (int g = bprev + 1; g <= bcur; ++g) gstart[g] = gid;
    }

    if (gid < 16384) {  // W frag pack: [mat(4)][k0(2)][c(4)][lane(64)][jj(8)]
        const int e = gid & 4095, mat = gid >> 12;
        const int jj = e & 7, lane = (e >> 3) & 63, c = (e >> 9) & 3, k0 = (e >> 11) & 1;
        const int k = k0 * 32 + (lane >> 4) * 8 + jj;
        const int col = c * 16 + (lane & 15);
        float val;
        if (mat == 0)      val = w0a[k * 64 + col] * (rsqrtf(v0[col] + BN_EPS) * g0[col]);
        else if (mat == 1) val = w0b[k * 64 + col];
        else if (mat == 2) val = w1a[k * 64 + col] * (rsqrtf(v1[col] + BN_EPS) * g1[col]);
        else               val = w1b[k * 64 + col];
        _Float16 hi = (_Float16)val;
        wHi[gid] = hi;
        wLo[gid] = (_Float16)(val - (float)hi);
    }

    if (gid >= 16384 && gid < 16512) {  // BN-folded biases
        int t = gid - 16384;
        if (t < 64) {
            float s = rsqrtf(v0[t] + BN_EPS) * g0[t];
            b1p0[t] = (b0a[t] - m0[t]) * s + be0[t];
        } else {
            t -= 64;
            float s = rsqrtf(v1[t] + BN_EPS) * g1[t];
            b1p1[t] = (b1a[t] - m1[t]) * s + be1[t];
        }
    }
}

// ---------------------------------------------------------------- single-pass scan
__global__ __launch_bounds__(256) void scan_lb_kernel(const int* __restrict__ deg,
                                                      unsigned long long* __restrict__ status,
                                                      int* __restrict__ rowptr) {
    __shared__ int sh[256];
    __shared__ int sbase;
    const int blk = blockIdx.x;
    const int t = threadIdx.x;
    const int i0 = blk * 512 + 2 * t, i1 = i0 + 1;
    const int d0 = (i0 < N_NODES) ? deg[i0] : 0;
    const int d1 = (i1 < N_NODES) ? deg[i1] : 0;
    const int p = d0 + d1;
    sh[t] = p;
    __syncthreads();
#pragma unroll
    for (int off = 1; off < 256; off <<= 1) {
        int u = (t >= off) ? sh[t - off] : 0;
        __syncthreads();
        sh[t] += u;
        __syncthreads();
    }
    const int agg = sh[255];
    if (t == 0) {
        if (blk == 0) {
            atomicExch(&status[0], (2ULL << 32) | (unsigned)agg);
            sbase = 0;
        } else {
            atomicExch(&status[blk], (1ULL << 32) | (unsigned)agg);
            int base = 0;
            int jb = blk - 1;
            while (jb >= 0) {
                unsigned long long s;
                do { s = atomicAdd(&status[jb], 0ULL); } while ((s >> 32) == 0);
                base += (int)(unsigned)s;
                if ((s >> 32) == 2ULL) break;
                --jb;
            }
            atomicExch(&status[blk], (2ULL << 32) | (unsigned)(base + agg));
            sbase = base;
        }
    }
    __syncthreads();
    const int excl = sbase + sh[t] - p;
    if (i0 < N_NODES) rowptr[i0] = excl;
    if (i1 < N_NODES) rowptr[i1] = excl + d0;
    if (blk == LB_NB - 1 && t == 255) rowptr[N_NODES] = N_EDGES;
}

__global__ __launch_bounds__(256) void fill_kernel(const int* __restrict__ srcI,
                                                   const int* __restrict__ dstI,
                                                   const int* __restrict__ rank,
                                                   const int* __restrict__ rowptr,
                                                   int* __restrict__ sortedSrc) {
    int e = blockIdx.x * 256 + threadIdx.x;
    if (e >= N_EDGES) return;
    sortedSrc[rowptr[dstI[e]] + rank[e]] = srcI[e];
}

// ---------------------------------------------------------------- fused conv (MFMA, fp16)
// Gather: lane = (edge-subindex j>>4, feature-chunk j&15), half4/lane -> 4 full
// 128B rows per wave instruction; ids per-lane from LDS-staged CSR slice.
// NOTE (R8 lesson): NO __threadfence / device-scope fences in this kernel —
// a per-block release fence invalidates L2 while other blocks are still
// gathering, collapsing gather hit rate (conv1 93 -> 210 us in R7/R8).
// Classifier stays a separate kernel for the same reason.
template <int POOL>
__global__ __launch_bounds__(256) void conv_mfma(
    const _Float16* __restrict__ in, const int* __restrict__ rowptr,
    const int* __restrict__ srcList,
    const _Float16* __restrict__ wH1, const _Float16* __restrict__ wL1,
    const _Float16* __restrict__ wH2, const _Float16* __restrict__ wL2,
    const float* __restrict__ b1, const float* __restrict__ b2,
    _Float16* __restrict__ out, const int* __restrict__ batch,
    float* __restrict__ pooled) {
    __shared__ __align__(16) _Float16 scratch[4][2304];  // per-wave aggH|aggL -> hH|hL -> oT
    __shared__ int ldsSrc[4][SCHUNK];
    __shared__ float pooledLoc[8 * 64];
    __shared__ int bIds[64];
    __shared__ int maxSlot;

    const int tid = threadIdx.x;
    const int j = tid & 63, wv = tid >> 6;
    const int eoff = j >> 4;    // edge sub-index within a 4-edge load group
    const int lf = j & 15;      // feature chunk (4 features)
    const int base = blockIdx.x * 64;
    const int strip0 = base + wv * 16;

    if (POOL) {
        pooledLoc[tid] = 0.f;
        pooledLoc[tid + 256] = 0.f;
        if (tid == 0) maxSlot = 0;
        if (j < 16) {
            int node = strip0 + j;
            bIds[wv * 16 + j] = (node < N_NODES) ? batch[node] : -1;
        }
    }

    // rowptr strip (17 values) in one vector load; broadcast via readlane
    const int rpv = rowptr[min(strip0 + min(j, 16), N_NODES)];
    const int sliceStart = __builtin_amdgcn_readlane(rpv, 0);
    const int sliceEnd = __builtin_amdgcn_readlane(rpv, 16);
    const int sliceLen = sliceEnd - sliceStart;

    for (int i = j; i < sliceLen && i < SCHUNK; i += 64)
        ldsSrc[wv][i] = srcList[sliceStart + i];

    _Float16* aggH = scratch[wv];
    _Float16* aggL = scratch[wv] + 1152;

#define GISSUE(K, TMP, CNT, R0LOC, EB)                                                \
    half4v TMP = {0, 0, 0, 0};                                                        \
    if ((K) < ((min((CNT) - (EB), 32) + 3) >> 2)) {                                   \
        int e_ = (EB) + 4 * (K) + eoff;                                               \
        int ec_ = min(e_, (CNT)-1);                                                   \
        int idx_ = (R0LOC) + ec_;                                                     \
        int id_ = (idx_ < SCHUNK) ? ldsSrc[wv][idx_] : srcList[sliceStart + idx_];    \
        TMP = *(const half4v*)(in + (size_t)id_ * 64 + lf * 4);                       \
    }
#define GCONS(K, TMP, CNT, EB, A)                                                     \
    if ((EB) + 4 * (K) + eoff < (CNT)) {                                              \
        A[0] += (float)TMP.x; A[1] += (float)TMP.y;                                   \
        A[2] += (float)TMP.z; A[3] += (float)TMP.w;                                   \
    }

    for (int mp = 0; mp < 8; ++mp) {
        const int mA = 2 * mp, mB = mA + 1;
        const int nodeA = strip0 + mA, nodeB = strip0 + mB;
        const int r0A = __builtin_amdgcn_readlane(rpv, mA);
        const int r1A = __builtin_amdgcn_readlane(rpv, mA + 1);
        const int r1B = __builtin_amdgcn_readlane(rpv, mB + 1);
        const int cntA = (nodeA < N_NODES) ? r1A - r0A : 0;
        const int cntB = (nodeB < N_NODES) ? r1B - r1A : 0;
        const int locA = r0A - sliceStart, locB = r1A - sliceStart;

        float aA[4] = {0.f, 0.f, 0.f, 0.f}, aB[4] = {0.f, 0.f, 0.f, 0.f};

        half4v sA = {0, 0, 0, 0}, sB = {0, 0, 0, 0};
        if (eoff == 0) {
            if (nodeA < N_NODES) sA = *(const half4v*)(in + (size_t)nodeA * 64 + lf * 4);
            if (nodeB < N_NODES) sB = *(const half4v*)(in + (size_t)nodeB * 64 + lf * 4);
        }

        // batched issue: first 32 edges of BOTH rows in flight before any consume
        {
            GISSUE(0, vA0, cntA, locA, 0) GISSUE(1, vA1, cntA, locA, 0)
            GISSUE(2, vA2, cntA, locA, 0) GISSUE(3, vA3, cntA, locA, 0)
            GISSUE(4, vA4, cntA, locA, 0) GISSUE(5, vA5, cntA, locA, 0)
            GISSUE(6, vA6, cntA, locA, 0) GISSUE(7, vA7, cntA, locA, 0)
            GISSUE(0, vB0, cntB, locB, 0) GISSUE(1, vB1, cntB, locB, 0)
            GISSUE(2, vB2, cntB, locB, 0) GISSUE(3, vB3, cntB, locB, 0)
            GISSUE(4, vB4, cntB, locB, 0) GISSUE(5, vB5, cntB, locB, 0)
            GISSUE(6, vB6, cntB, locB, 0) GISSUE(7, vB7, cntB, locB, 0)
            GCONS(0, vA0, cntA, 0, aA) GCONS(1, vA1, cntA, 0, aA)
            GCONS(2, vA2, cntA, 0, aA) GCONS(3, vA3, cntA, 0, aA)
            GCONS(4, vA4, cntA, 0, aA) GCONS(5, vA5, cntA, 0, aA)
            GCONS(6, vA6, cntA, 0, aA) GCONS(7, vA7, cntA, 0, aA)
            GCONS(0, vB0, cntB, 0, aB) GCONS(1, vB1, cntB, 0, aB)
            GCONS(2, vB2, cntB, 0, aB) GCONS(3, vB3, cntB, 0, aB)
            GCONS(4, vB4, cntB, 0, aB) GCONS(5, vB5, cntB, 0, aB)
            GCONS(6, vB6, cntB, 0, aB) GCONS(7, vB7, cntB, 0, aB)
        }
        // rare tails (> 32 edges per row)
        for (int eb = 32; eb < cntA; eb += 32) {
            GISSUE(0, w0, cntA, locA, eb) GISSUE(1, w1, cntA, locA, eb)
            GISSUE(2, w2, cntA, locA, eb) GISSUE(3, w3, cntA, locA, eb)
            GISSUE(4, w4, cntA, locA, eb) GISSUE(5, w5, cntA, locA, eb)
            GISSUE(6, w6, cntA, locA, eb) GISSUE(7, w7, cntA, locA, eb)
            GCONS(0, w0, cntA, eb, aA) GCONS(1, w1, cntA, eb, aA)
            GCONS(2, w2, cntA, eb, aA) GCONS(3, w3, cntA, eb, aA)
            GCONS(4, w4, cntA, eb, aA) GCONS(5, w5, cntA, eb, aA)
            GCONS(6, w6, cntA, eb, aA) GCONS(7, w7, cntA, eb, aA)
        }
        for (int eb = 32; eb < cntB; eb += 32) {
            GISSUE(0, w0, cntB, locB, eb) GISSUE(1, w1, cntB, locB, eb)
            GISSUE(2, w2, cntB, locB, eb) GISSUE(3, w3, cntB, locB, eb)
            GISSUE(4, w4, cntB, locB, eb) GISSUE(5, w5, cntB, locB, eb)
            GISSUE(6, w6, cntB, locB, eb) GISSUE(7, w7, cntB, locB, eb)
            GCONS(0, w0, cntB, eb, aB) GCONS(1, w1, cntB, eb, aB)
            GCONS(2, w2, cntB, eb, aB) GCONS(3, w3, cntB, eb, aB)
            GCONS(4, w4, cntB, eb, aB) GCONS(5, w5, cntB, eb, aB)
            GCONS(6, w6, cntB, eb, aB) GCONS(7, w7, cntB, eb, aB)
        }
        if (eoff == 0) {
            aA[0] += (float)sA.x; aA[1] += (float)sA.y; aA[2] += (float)sA.z; aA[3] += (float)sA.w;
            aB[0] += (float)sB.x; aB[1] += (float)sB.y; aB[2] += (float)sB.z; aB[3] += (float)sB.w;
        }
#pragma unroll
        for (int i = 0; i < 4; ++i) {
            aA[i] += __shfl_xor(aA[i], 16, 64);
            aA[i] += __shfl_xor(aA[i], 32, 64);
            aB[i] += __shfl_xor(aB[i], 16, 64);
            aB[i] += __shfl_xor(aB[i], 32, 64);
        }
        if (j < 16) {
            half4v hiA, loA, hiB, loB;
#pragma unroll
            for (int i = 0; i < 4; ++i) {
                hiA[i] = (_Float16)aA[i]; loA[i] = (_Float16)(aA[i] - (float)hiA[i]);
                hiB[i] = (_Float16)aB[i]; loB[i] = (_Float16)(aB[i] - (float)hiB[i]);
            }
            *(half4v*)(aggH + mA * 72 + 4 * j) = hiA;
            *(half4v*)(aggL + mA * 72 + 4 * j) = loA;
            *(half4v*)(aggH + mB * 72 + 4 * j) = hiB;
            *(half4v*)(aggL + mB * 72 + 4 * j) = loB;
        }
    }
#undef GISSUE
#undef GCONS

    const int l15 = j & 15, quad = j >> 4;
    const floatx4 vzero = {0.f, 0.f, 0.f, 0.f};

    // ---- linear1 (+BN fold) ----
    floatx4 acc[4] = {vzero, vzero, vzero, vzero};
    {
        const _Float16* aH0 = aggH + l15 * 72 + quad * 8;
        const _Float16* aL0 = aggL + l15 * 72 + quad * 8;
#pragma unroll
        for (int k0 = 0; k0 < 2; ++k0) {
            half8 aH = *(const half8*)(aH0 + k0 * 32);
            half8 aL = *(const half8*)(aL0 + k0 * 32);
#pragma unroll
            for (int c = 0; c < 4; ++c) {
                const int fo = ((k0 * 4 + c) * 64 + j) * 8;
                half8 bH = *(const half8*)(wH1 + fo);
                half8 bL = *(const half8*)(wL1 + fo);
                acc[c] = __builtin_amdgcn_mfma_f32_16x16x32_f16(aH, bH, acc[c], 0, 0, 0);
                acc[c] = __builtin_amdgcn_mfma_f32_16x16x32_f16(aL, bH, acc[c], 0, 0, 0);
                acc[c] = __builtin_amdgcn_mfma_f32_16x16x32_f16(aH, bL, acc[c], 0, 0, 0);
            }
        }
    }
    _Float16* hH = aggH;
    _Float16* hL = aggL;
#pragma unroll
    for (int c = 0; c < 4; ++c) {
        const float bv = b1[c * 16 + l15];
#pragma unroll
        for (int r = 0; r < 4; ++r) {
            const int row = quad * 4 + r, col = c * 16 + l15;
            float v = acc[c][r] + bv;
            v = fmaxf(v, 0.f);
            const _Float16 hi = (_Float16)v;
            hH[row * 72 + col] = hi;
            hL[row * 72 + col] = (_Float16)(v - (float)hi);
        }
    }

    // ---- linear2 ----
    floatx4 acc2[4] = {vzero, vzero, vzero, vzero};
    {
        const _Float16* aH0 = hH + l15 * 72 + quad * 8;
        const _Float16* aL0 = hL + l15 * 72 + quad * 8;
#pragma unroll
        for (int k0 = 0; k0 < 2; ++k0) {
            half8 aH = *(const half8*)(aH0 + k0 * 32);
            half8 aL = *(const half8*)(aL0 + k0 * 32);
#pragma unroll
            for (int c = 0; c < 4; ++c) {
                const int fo = ((k0 * 4 + c) * 64 + j) * 8;
                half8 bH = *(const half8*)(wH2 + fo);
                half8 bL = *(const half8*)(wL2 + fo);
                acc2[c] = __builtin_amdgcn_mfma_f32_16x16x32_f16(aH, bH, acc2[c], 0, 0, 0);
                acc2[c] = __builtin_amdgcn_mfma_f32_16x16x32_f16(aL, bH, acc2[c], 0, 0, 0);
                acc2[c] = __builtin_amdgcn_mfma_f32_16x16x32_f16(aH, bL, acc2[c], 0, 0, 0);
            }
        }
    }

    // ---- epilogue ----
    if (!POOL) {
#pragma unroll
        for (int c = 0; c < 4; ++c) {
            const float bv = b2[c * 16 + l15];
#pragma unroll
            for (int r = 0; r < 4; ++r) {
                const int node = strip0 + quad * 4 + r;
                if (node < N_NODES)
                    out[(size_t)node * 64 + c * 16 + l15] =
                        (_Float16)fmaxf(acc2[c][r] + bv, 0.f);
            }
        }
    } else {
        float* oT = (float*)scratch[wv];  // 16 x 66, wave-private (H reads done)
#pragma unroll
        for (int c = 0; c < 4; ++c) {
            const float bv = b2[c * 16 + l15];
#pragma unroll
            for (int r = 0; r < 4; ++r)
                oT[(quad * 4 + r) * 66 + c * 16 + l15] = acc2[c][r] + bv;
        }
        __syncthreads();
        const int b0 = bIds[0];
        int curB = -1;
        float accv = 0.f;
        for (int r = 0; r < 16; ++r) {
            const int b = bIds[wv * 16 + r];  // wave-uniform
            if (b < 0) break;
            const float v = oT[r * 66 + j];
            if (b != curB) {
                if (curB >= 0) {
                    const int s = curB - b0;
                    if (s >= 0 && s < 8) {
                        atomicAdd(&pooledLoc[s * 64 + j], accv);
                        if (j == 0) atomicMax(&maxSlot, s);
                    } else {
                        atomicAdd(&pooled[curB * 64 + j], accv);
                    }
                }
                curB = b;
                accv = v;
            } else {
                accv += v;
            }
        }
        if (curB >= 0) {
            const int s = curB - b0;
            if (s >= 0 && s < 8) {
                atomicAdd(&pooledLoc[s * 64 + j], accv);
                if (j == 0) atomicMax(&maxSlot, s);
            } else {
                atomicAdd(&pooled[curB * 64 + j], accv);
            }
        }
        __syncthreads();
        if (b0 >= 0) {
            const int ns = maxSlot + 1;
            for (int s = wv; s < ns; s += 4)
                atomicAdd(&pooled[(b0 + s) * 64 + j], pooledLoc[s * 64 + j]);
        }
    }
}

// ---------------------------------------------------------------- classifier
__global__ __launch_bounds__(64) void classifier_kernel(const float* __restrict__ pooled,
                                                        const int* __restrict__ gstart,
                                                        const float* __restrict__ wc,
                                                        const float* __restrict__ bc,
                                                        float* __restrict__ out) {
    const int g = blockIdx.x;
    const int j = threadIdx.x;
    const float c = fmaxf((float)(gstart[g + 1] - gstart[g]), 1.f);
    const float mean = pooled[g * 64 + j] / c;
#pragma unroll
    for (int cc = 0; cc < N_CLS; ++cc) {
        float p = mean * wc[j * N_CLS + cc];
#pragma unroll
        for (int off = 32; off > 0; off >>= 1) p += __shfl_down(p, off, 64);
        if (j == 0) out[g * N_CLS + cc] = p + bc[cc];
    }
}

// ---------------------------------------------------------------- launch

extern "C" void kernel_launch(void* const* d_in, const int* in_sizes, int n_in,
                              void* d_out, int out_size, void* d_ws, size_t ws_size,
                              hipStream_t stream) {
    const float* x   = (const float*)d_in[0];
    const int*   ei  = (const int*)d_in[1];
    const int* batch = (const int*)d_in[2];
    const float* w0a = (const float*)d_in[3];
    const float* b0a = (const float*)d_in[4];
    const float* g0  = (const float*)d_in[5];
    const float* be0 = (const float*)d_in[6];
    const float* m0  = (const float*)d_in[7];
    const float* v0  = (const float*)d_in[8];
    const float* w0b = (const float*)d_in[9];
    const float* b0b = (const float*)d_in[10];
    const float* w1a = (const float*)d_in[11];
    const float* b1a = (const float*)d_in[12];
    const float* g1  = (const float*)d_in[13];
    const float* be1 = (const float*)d_in[14];
    const float* m1  = (const float*)d_in[15];
    const float* v1  = (const float*)d_in[16];
    const float* w1b = (const float*)d_in[17];
    const float* b1b = (const float*)d_in[18];
    const float* wc  = (const float*)d_in[19];
    const float* bc  = (const float*)d_in[20];
    float* out = (float*)d_out;

    const int* srcI = ei;
    const int* dstI = ei + N_EDGES;

    // workspace layout, offsets in 4-byte units
    int* ws = (int*)d_ws;
    int*      deg       = ws;                              // 100000
    unsigned long long* status = (unsigned long long*)(ws + 100000);  // 200 u64
    int*      doneCnt   = ws + 100400;                     // 4 (unused; kept for layout)
    float*    pooled    = (float*)(ws + 100404);           // 32768
    int*      rowptr    = ws + 133172;                     // 100001
    int*      rank      = ws + 233176;                     // 1000000
    int*      sortedSrc = ws + 1233176;                    // 1000000
    _Float16* xh        = (_Float16*)(ws + 2233176);       // 6400000 halves
    _Float16* h1        = (_Float16*)(ws + 5433176);       // 6400000 halves
    float*    b1p0      = (float*)(ws + 8633176);          // 64
    float*    b1p1      = (float*)(ws + 8633240);          // 64
    int*      gstart    = ws + 8633304;                    // 513
    _Float16* wHi       = (_Float16*)(ws + 8633820);       // 16384 halves
    _Float16* wLo       = (_Float16*)(ws + 8642012);       // 16384 halves
    (void)doneCnt;

    hipMemsetAsync((void*)deg, 0, 133172 * sizeof(int), stream);
    prep_kernel<<<6250, 256, 0, stream>>>(x, xh, batch, dstI, deg, rank,
                                          w0a, b0a, g0, be0, m0, v0, w0b,
                                          w1a, b1a, g1, be1, m1, v1, w1b,
                                          gstart, wHi, wLo, b1p0, b1p1);

    scan_lb_kernel<<<LB_NB, 256, 0, stream>>>(deg, status, rowptr);
    fill_kernel<<<(N_EDGES + 255) / 256, 256, 0, stream>>>(srcI, dstI, rank, rowptr, sortedSrc);

    // conv0: h1 = relu(mlp0(x + gather(x)))   [fp16 features]
    conv_mfma<0><<<NTILES, 256, 0, stream>>>(xh, rowptr, sortedSrc,
                                             wHi, wLo, wHi + 4096, wLo + 4096,
                                             b1p0, b0b, h1, nullptr, nullptr);

    // conv1: pooled += mlp1(h1 + gather(h1))
    conv_mfma<1><<<NTILES, 256, 0, stream>>>(h1, rowptr, sortedSrc,
                                             wHi + 8192, wLo + 8192, wHi + 12288, wLo + 12288,
                                             b1p1, b1b, nullptr, batch, pooled);

    // classifier: separate tiny kernel (fence-free pipeline)
    classifier_kernel<<<N_GRAPHS, 64, 0, stream>>>(pooled, gstart, wc, bc, out);
}

// Round 10
// 306.275 us; speedup vs baseline: 1.4662x; 1.0090x over previous
//
#include <hip/hip_runtime.h>

#define N_NODES 100000
#define N_EDGES 1000000
#define N_GRAPHS 512
#define N_CLS 10
#define BN_EPS 1e-5f

#define SCAN_NB 200   // 200 * 512 = 102400 >= N_NODES
#define NTILES 1563   // ceil(100000/64)

typedef _Float16 half8 __attribute__((ext_vector_type(8)));
typedef _Float16 half4v __attribute__((ext_vector_type(4)));
typedef float floatx4 __attribute__((ext_vector_type(4)));

// ---------------------------------------------------------------- prep
__global__ __launch_bounds__(256) void prep_kernel(
    const float* __restrict__ x, _Float16* __restrict__ xh,
    const int* __restrict__ batch, const int* __restrict__ dstI,
    int* __restrict__ deg, int* __restrict__ rank,
    const float* __restrict__ w0a, const float* __restrict__ b0a,
    const float* __restrict__ g0, const float* __restrict__ be0,
    const float* __restrict__ m0, const float* __restrict__ v0,
    const float* __restrict__ w0b,
    const float* __restrict__ w1a, const float* __restrict__ b1a,
    const float* __restrict__ g1, const float* __restrict__ be1,
    const float* __restrict__ m1, const float* __restrict__ v1,
    const float* __restrict__ w1b,
    int* __restrict__ gstart,
    _Float16* __restrict__ wHi, _Float16* __restrict__ wLo,
    float* __restrict__ b1p0, float* __restrict__ b1p1) {
    const int gid = blockIdx.x * 256 + threadIdx.x;

    if (gid < 1600000) {  // x -> fp16 (6.4M elems as float4 -> half4)
        float4 v = ((const float4*)x)[gid];
        half4v h = {(_Float16)v.x, (_Float16)v.y, (_Float16)v.z, (_Float16)v.w};
        ((half4v*)xh)[gid] = h;
    }

    if (gid < N_EDGES)  // histogram + per-edge rank within dst bucket
        rank[gid] = atomicAdd(&deg[dstI[gid]], 1);

    if (gid <= N_NODES) {  // graph boundaries from sorted batch
        int bcur = (gid < N_NODES) ? batch[gid] : N_GRAPHS;
        int bprev = (gid > 0) ? batch[gid - 1] : -1;
        for (int g = bprev + 1; g <= bcur; ++g) gstart[g] = gid;
    }

    if (gid < 16384) {  // W frag pack: [mat(4)][k0(2)][c(4)][lane(64)][jj(8)]
        const int e = gid & 4095, mat = gid >> 12;
        const int jj = e & 7, lane = (e >> 3) & 63, c = (e >> 9) & 3, k0 = (e >> 11) & 1;
        const int k = k0 * 32 + (lane >> 4) * 8 + jj;
        const int col = c * 16 + (lane & 15);
        float val;
        if (mat == 0)      val = w0a[k * 64 + col] * (rsqrtf(v0[col] + BN_EPS) * g0[col]);
        else if (mat == 1) val = w0b[k * 64 + col];
        else if (mat == 2) val = w1a[k * 64 + col] * (rsqrtf(v1[col] + BN_EPS) * g1[col]);
        else               val = w1b[k * 64 + col];
        _Float16 hi = (_Float16)val;
        wHi[gid] = hi;
        wLo[gid] = (_Float16)(val - (float)hi);
    }

    if (gid >= 16384 && gid < 16512) {  // BN-folded biases
        int t = gid - 16384;
        if (t < 64) {
            float s = rsqrtf(v0[t] + BN_EPS) * g0[t];
            b1p0[t] = (b0a[t] - m0[t]) * s + be0[t];
        } else {
            t -= 64;
            float s = rsqrtf(v1[t] + BN_EPS) * g1[t];
            b1p1[t] = (b1a[t] - m1[t]) * s + be1[t];
        }
    }
}

// ---------------------------------------------------------------- 3-kernel scan
// (R9 lesson: decoupled lookback serializes ~O(blocks) atomic polls; the
// 3-phase scan's phases are each fully parallel and measured-cheap.)
__global__ __launch_bounds__(256) void scanA_kernel(const int* __restrict__ deg,
                                                    int* __restrict__ bsum) {
    __shared__ int sh[256];
    const int base = blockIdx.x * 512;
    const int t = threadIdx.x;
    int a = 0, b = 0;
    if (base + t < N_NODES) a = deg[base + t];
    if (base + 256 + t < N_NODES) b = deg[base + 256 + t];
    sh[t] = a + b;
    __syncthreads();
#pragma unroll
    for (int off = 128; off > 0; off >>= 1) {
        if (t < off) sh[t] += sh[t + off];
        __syncthreads();
    }
    if (t == 0) bsum[blockIdx.x] = sh[0];
}

__global__ __launch_bounds__(256) void scanB_kernel(const int* __restrict__ bsum,
                                                    int* __restrict__ boff,
                                                    int* __restrict__ rowptr) {
    __shared__ int sh[256];
    const int t = threadIdx.x;
    const int v = (t < SCAN_NB) ? bsum[t] : 0;
    sh[t] = v;
    __syncthreads();
#pragma unroll
    for (int off = 1; off < 256; off <<= 1) {
        int u = (t >= off) ? sh[t - off] : 0;
        __syncthreads();
        sh[t] += u;
        __syncthreads();
    }
    if (t < SCAN_NB) boff[t] = sh[t] - v;
    if (t == 0) rowptr[N_NODES] = N_EDGES;
}

__global__ __launch_bounds__(256) void scanC_kernel(const int* __restrict__ deg,
                                                    const int* __restrict__ boff,
                                                    int* __restrict__ rowptr) {
    __shared__ int sh[256];
    const int base = blockIdx.x * 512;
    const int t = threadIdx.x;
    const int i0 = base + 2 * t, i1 = i0 + 1;
    const int d0 = (i0 < N_NODES) ? deg[i0] : 0;
    const int d1 = (i1 < N_NODES) ? deg[i1] : 0;
    const int p = d0 + d1;
    sh[t] = p;
    __syncthreads();
#pragma unroll
    for (int off = 1; off < 256; off <<= 1) {
        int u = (t >= off) ? sh[t - off] : 0;
        __syncthreads();
        sh[t] += u;
        __syncthreads();
    }
    const int excl = boff[blockIdx.x] + sh[t] - p;
    if (i0 < N_NODES) rowptr[i0] = excl;
    if (i1 < N_NODES) rowptr[i1] = excl + d0;
}

__global__ __launch_bounds__(256) void fill_kernel(const int* __restrict__ srcI,
                                                   const int* __restrict__ dstI,
                                                   const int* __restrict__ rank,
                                                   const int* __restrict__ rowptr,
                                                   int* __restrict__ sortedSrc) {
    int e = blockIdx.x * 256 + threadIdx.x;
    if (e >= N_EDGES) return;
    sortedSrc[rowptr[dstI[e]] + rank[e]] = srcI[e];
}

// ---------------------------------------------------------------- fused conv (MFMA, fp16)
// Gather: lane = (edge-subindex j>>4, feature-chunk j&15), half4/lane -> 4 full
// 128B rows per wave instruction. 4 rows x 4 edge-groups issued per batch under
// UNIFORM guards (clamped indices) -> ~20 loads in flight before any wait.
// Ids read per-lane directly from srcList (only 4 distinct per instr, L2-hit).
// LDS ~21KB -> 7 blocks/CU (28 waves); 1563 blocks <= 1792 = single round.
// NO device-scope fences anywhere (R8 lesson: fence collapses gather L2 hits).
template <int POOL>
__global__ __launch_bounds__(256) void conv_mfma(
    const _Float16* __restrict__ in, const int* __restrict__ rowptr,
    const int* __restrict__ srcList,
    const _Float16* __restrict__ wH1, const _Float16* __restrict__ wL1,
    const _Float16* __restrict__ wH2, const _Float16* __restrict__ wL2,
    const float* __restrict__ b1, const float* __restrict__ b2,
    _Float16* __restrict__ out, const int* __restrict__ batch,
    float* __restrict__ pooled) {
    __shared__ __align__(16) _Float16 scratch[4][2304];  // per-wave aggH|aggL -> hH|hL -> oT
    __shared__ float pooledLoc[8 * 64];
    __shared__ int bIds[64];
    __shared__ int maxSlot;

    const int tid = threadIdx.x;
    const int j = tid & 63, wv = tid >> 6;
    const int eoff = j >> 4;    // edge sub-index within a 4-edge load group
    const int lf = j & 15;      // feature chunk (4 features)
    const int base = blockIdx.x * 64;
    const int strip0 = base + wv * 16;

    if (POOL) {
        pooledLoc[tid] = 0.f;
        pooledLoc[tid + 256] = 0.f;
        if (tid == 0) maxSlot = 0;
        if (j < 16) {
            int node = strip0 + j;
            bIds[wv * 16 + j] = (node < N_NODES) ? batch[node] : -1;
        }
    }

    // rowptr strip (17 values) in one vector load; broadcast via readlane
    const int rpv = rowptr[min(strip0 + min(j, 16), N_NODES)];

    _Float16* aggH = scratch[wv];
    _Float16* aggL = scratch[wv] + 1152;

    for (int mq = 0; mq < 4; ++mq) {
        const int m0 = mq * 4;
        int rr[5];
#pragma unroll
        for (int i = 0; i < 5; ++i) rr[i] = __builtin_amdgcn_readlane(rpv, m0 + i);
        int cnt[4];
#pragma unroll
        for (int i = 0; i < 4; ++i)
            cnt[i] = (strip0 + m0 + i < N_NODES) ? rr[i + 1] - rr[i] : 0;

        float aR[4][4];
#pragma unroll
        for (int i = 0; i < 4; ++i)
#pragma unroll
            for (int q = 0; q < 4; ++q) aR[i][q] = 0.f;

        // ---- issue phase: 4 selfs + up to 16 edge-group loads, all in flight ----
        half4v sS[4];
#pragma unroll
        for (int i = 0; i < 4; ++i) {
            sS[i] = (half4v){0, 0, 0, 0};
            if (eoff == 0 && strip0 + m0 + i < N_NODES)
                sS[i] = *(const half4v*)(in + (size_t)(strip0 + m0 + i) * 64 + lf * 4);
        }
        half4v vT[4][4];
#pragma unroll
        for (int i = 0; i < 4; ++i) {
            const int g = (min(cnt[i], 16) + 3) >> 2;  // groups needed (uniform)
#pragma unroll
            for (int k = 0; k < 4; ++k) {
                vT[i][k] = (half4v){0, 0, 0, 0};
                if (k < g) {
                    int ec = min(4 * k + eoff, cnt[i] - 1);   // clamp: load stays in-row
                    int id = srcList[rr[i] + ec];
                    vT[i][k] = *(const half4v*)(in + (size_t)id * 64 + lf * 4);
                }
            }
        }
        // ---- consume phase ----
#pragma unroll
        for (int i = 0; i < 4; ++i) {
#pragma unroll
            for (int k = 0; k < 4; ++k) {
                if (4 * k + eoff < cnt[i]) {
                    aR[i][0] += (float)vT[i][k].x; aR[i][1] += (float)vT[i][k].y;
                    aR[i][2] += (float)vT[i][k].z; aR[i][3] += (float)vT[i][k].w;
                }
            }
        }
        // rare tails (deg > 16, ~3% of rows): per-lane predicated
#pragma unroll
        for (int i = 0; i < 4; ++i) {
            for (int eb = 16; eb < cnt[i]; eb += 16) {
#pragma unroll
                for (int k = 0; k < 4; ++k) {
                    int e_ = eb + 4 * k + eoff;
                    if (e_ < cnt[i]) {
                        int id = srcList[rr[i] + e_];
                        half4v t = *(const half4v*)(in + (size_t)id * 64 + lf * 4);
                        aR[i][0] += (float)t.x; aR[i][1] += (float)t.y;
                        aR[i][2] += (float)t.z; aR[i][3] += (float)t.w;
                    }
                }
            }
        }
        // self + cross-group reduce + hi/lo split to LDS
#pragma unroll
        for (int i = 0; i < 4; ++i) {
            if (eoff == 0) {
                aR[i][0] += (float)sS[i].x; aR[i][1] += (float)sS[i].y;
                aR[i][2] += (float)sS[i].z; aR[i][3] += (float)sS[i].w;
            }
#pragma unroll
            for (int q = 0; q < 4; ++q) {
                aR[i][q] += __shfl_xor(aR[i][q], 16, 64);
                aR[i][q] += __shfl_xor(aR[i][q], 32, 64);
            }
            if (j < 16) {
                half4v hi, lo;
#pragma unroll
                for (int q = 0; q < 4; ++q) {
                    hi[q] = (_Float16)aR[i][q];
                    lo[q] = (_Float16)(aR[i][q] - (float)hi[q]);
                }
                *(half4v*)(aggH + (m0 + i) * 72 + 4 * j) = hi;
                *(half4v*)(aggL + (m0 + i) * 72 + 4 * j) = lo;
            }
        }
    }

    const int l15 = j & 15, quad = j >> 4;
    const floatx4 vzero = {0.f, 0.f, 0.f, 0.f};

    // ---- linear1 (+BN fold) ----  (A rows are wave-private: no barrier needed)
    floatx4 acc[4] = {vzero, vzero, vzero, vzero};
    {
        const _Float16* aH0 = aggH + l15 * 72 + quad * 8;
        const _Float16* aL0 = aggL + l15 * 72 + quad * 8;
#pragma unroll
        for (int k0 = 0; k0 < 2; ++k0) {
            half8 aH = *(const half8*)(aH0 + k0 * 32);
            half8 aL = *(const half8*)(aL0 + k0 * 32);
#pragma unroll
            for (int c = 0; c < 4; ++c) {
                const int fo = ((k0 * 4 + c) * 64 + j) * 8;
                half8 bH = *(const half8*)(wH1 + fo);
                half8 bL = *(const half8*)(wL1 + fo);
                acc[c] = __builtin_amdgcn_mfma_f32_16x16x32_f16(aH, bH, acc[c], 0, 0, 0);
                acc[c] = __builtin_amdgcn_mfma_f32_16x16x32_f16(aL, bH, acc[c], 0, 0, 0);
                acc[c] = __builtin_amdgcn_mfma_f32_16x16x32_f16(aH, bL, acc[c], 0, 0, 0);
            }
        }
    }
    _Float16* hH = aggH;
    _Float16* hL = aggL;
#pragma unroll
    for (int c = 0; c < 4; ++c) {
        const float bv = b1[c * 16 + l15];
#pragma unroll
        for (int r = 0; r < 4; ++r) {
            const int row = quad * 4 + r, col = c * 16 + l15;
            float v = acc[c][r] + bv;
            v = fmaxf(v, 0.f);
            const _Float16 hi = (_Float16)v;
            hH[row * 72 + col] = hi;
            hL[row * 72 + col] = (_Float16)(v - (float)hi);
        }
    }

    // ---- linear2 ----
    floatx4 acc2[4] = {vzero, vzero, vzero, vzero};
    {
        const _Float16* aH0 = hH + l15 * 72 + quad * 8;
        const _Float16* aL0 = hL + l15 * 72 + quad * 8;
#pragma unroll
        for (int k0 = 0; k0 < 2; ++k0) {
            half8 aH = *(const half8*)(aH0 + k0 * 32);
            half8 aL = *(const half8*)(aL0 + k0 * 32);
#pragma unroll
            for (int c = 0; c < 4; ++c) {
                const int fo = ((k0 * 4 + c) * 64 + j) * 8;
                half8 bH = *(const half8*)(wH2 + fo);
                half8 bL = *(const half8*)(wL2 + fo);
                acc2[c] = __builtin_amdgcn_mfma_f32_16x16x32_f16(aH, bH, acc2[c], 0, 0, 0);
                acc2[c] = __builtin_amdgcn_mfma_f32_16x16x32_f16(aL, bH, acc2[c], 0, 0, 0);
                acc2[c] = __builtin_amdgcn_mfma_f32_16x16x32_f16(aH, bL, acc2[c], 0, 0, 0);
            }
        }
    }

    // ---- epilogue ----
    if (!POOL) {
#pragma unroll
        for (int c = 0; c < 4; ++c) {
            const float bv = b2[c * 16 + l15];
#pragma unroll
            for (int r = 0; r < 4; ++r) {
                const int node = strip0 + quad * 4 + r;
                if (node < N_NODES)
                    out[(size_t)node * 64 + c * 16 + l15] =
                        (_Float16)fmaxf(acc2[c][r] + bv, 0.f);
            }
        }
    } else {
        float* oT = (float*)scratch[wv];  // 16 x 66, wave-private (H reads done)
#pragma unroll
        for (int c = 0; c < 4; ++c) {
            const float bv = b2[c * 16 + l15];
#pragma unroll
            for (int r = 0; r < 4; ++r)
                oT[(quad * 4 + r) * 66 + c * 16 + l15] = acc2[c][r] + bv;
        }
        __syncthreads();
        const int b0 = bIds[0];
        int curB = -1;
        float accv = 0.f;
        for (int r = 0; r < 16; ++r) {
            const int b = bIds[wv * 16 + r];  // wave-uniform
            if (b < 0) break;
            const float v = oT[r * 66 + j];
            if (b != curB) {
                if (curB >= 0) {
                    const int s = curB - b0;
                    if (s >= 0 && s < 8) {
                        atomicAdd(&pooledLoc[s * 64 + j], accv);
                        if (j == 0) atomicMax(&maxSlot, s);
                    } else {
                        atomicAdd(&pooled[curB * 64 + j], accv);
                    }
                }
                curB = b;
                accv = v;
            } else {
                accv += v;
            }
        }
        if (curB >= 0) {
            const int s = curB - b0;
            if (s >= 0 && s < 8) {
                atomicAdd(&pooledLoc[s * 64 + j], accv);
                if (j == 0) atomicMax(&maxSlot, s);
            } else {
                atomicAdd(&pooled[curB * 64 + j], accv);
            }
        }
        __syncthreads();
        if (b0 >= 0) {
            const int ns = maxSlot + 1;
            for (int s = wv; s < ns; s += 4)
                atomicAdd(&pooled[(b0 + s) * 64 + j], pooledLoc[s * 64 + j]);
        }
    }
}

// ---------------------------------------------------------------- classifier
__global__ __launch_bounds__(64) void classifier_kernel(const float* __restrict__ pooled,
                                                        const int* __restrict__ gstart,
                                                        const float* __restrict__ wc,
                                                        const float* __restrict__ bc,
                                                        float* __restrict__ out) {
    const int g = blockIdx.x;
    const int j = threadIdx.x;
    const float c = fmaxf((float)(gstart[g + 1] - gstart[g]), 1.f);
    const float mean = pooled[g * 64 + j] / c;
#pragma unroll
    for (int cc = 0; cc < N_CLS; ++cc) {
        float p = mean * wc[j * N_CLS + cc];
#pragma unroll
        for (int off = 32; off > 0; off >>= 1) p += __shfl_down(p, off, 64);
        if (j == 0) out[g * N_CLS + cc] = p + bc[cc];
    }
}

// ---------------------------------------------------------------- launch

extern "C" void kernel_launch(void* const* d_in, const int* in_sizes, int n_in,
                              void* d_out, int out_size, void* d_ws, size_t ws_size,
                              hipStream_t stream) {
    const float* x   = (const float*)d_in[0];
    const int*   ei  = (const int*)d_in[1];
    const int* batch = (const int*)d_in[2];
    const float* w0a = (const float*)d_in[3];
    const float* b0a = (const float*)d_in[4];
    const float* g0  = (const float*)d_in[5];
    const float* be0 = (const float*)d_in[6];
    const float* m0  = (const float*)d_in[7];
    const float* v0  = (const float*)d_in[8];
    const float* w0b = (const float*)d_in[9];
    const float* b0b = (const float*)d_in[10];
    const float* w1a = (const float*)d_in[11];
    const float* b1a = (const float*)d_in[12];
    const float* g1  = (const float*)d_in[13];
    const float* be1 = (const float*)d_in[14];
    const float* m1  = (const float*)d_in[15];
    const float* v1  = (const float*)d_in[16];
    const float* w1b = (const float*)d_in[17];
    const float* b1b = (const float*)d_in[18];
    const float* wc  = (const float*)d_in[19];
    const float* bc  = (const float*)d_in[20];
    float* out = (float*)d_out;

    const int* srcI = ei;
    const int* dstI = ei + N_EDGES;

    // workspace layout, offsets in 4-byte units
    int* ws = (int*)d_ws;
    int*      deg       = ws;                              // 100000
    int*      bsum      = ws + 100000;                     // 200
    int*      boff      = ws + 100200;                     // 200
    float*    pooled    = (float*)(ws + 100404);           // 32768
    int*      rowptr    = ws + 133172;                     // 100001
    int*      rank      = ws + 233176;                     // 1000000
    int*      sortedSrc = ws + 1233176;                    // 1000000
    _Float16* xh        = (_Float16*)(ws + 2233176);       // 6400000 halves
    _Float16* h1        = (_Float16*)(ws + 5433176);       // 6400000 halves
    float*    b1p0      = (float*)(ws + 8633176);          // 64
    float*    b1p1      = (float*)(ws + 8633240);          // 64
    int*      gstart    = ws + 8633304;                    // 513
    _Float16* wHi       = (_Float16*)(ws + 8633820);       // 16384 halves
    _Float16* wLo       = (_Float16*)(ws + 8642012);       // 16384 halves

    hipMemsetAsync((void*)deg, 0, 133172 * sizeof(int), stream);
    prep_kernel<<<6250, 256, 0, stream>>>(x, xh, batch, dstI, deg, rank,
                                          w0a, b0a, g0, be0, m0, v0, w0b,
                                          w1a, b1a, g1, be1, m1, v1, w1b,
                                          gstart, wHi, wLo, b1p0, b1p1);

    scanA_kernel<<<SCAN_NB, 256, 0, stream>>>(deg, bsum);
    scanB_kernel<<<1, 256, 0, stream>>>(bsum, boff, rowptr);
    scanC_kernel<<<SCAN_NB, 256, 0, stream>>>(deg, boff, rowptr);
    fill_kernel<<<(N_EDGES + 255) / 256, 256, 0, stream>>>(srcI, dstI, rank, rowptr, sortedSrc);

    // conv0: h1 = relu(mlp0(x + gather(x)))   [fp16 features]
    conv_mfma<0><<<NTILES, 256, 0, stream>>>(xh, rowptr, sortedSrc,
                                             wHi, wLo, wHi + 4096, wLo + 4096,
                                             b1p0, b0b, h1, nullptr, nullptr);

    // conv1: pooled += mlp1(h1 + gather(h1))
    conv_mfma<1><<<NTILES, 256, 0, stream>>>(h1, rowptr, sortedSrc,
                                             wHi + 8192, wLo + 8192, wHi + 12288, wLo + 12288,
                                             b1p1, b1b, nullptr, batch, pooled);

    // classifier: separate tiny kernel (fence-free pipeline)
    classifier_kernel<<<N_GRAPHS, 64, 0, stream>>>(pooled, gstart, wc, bc, out);
}